// Round 15
// baseline (1351.417 us; speedup 1.0000x reference)
//
#include <hip/hip_runtime.h>

#define DD 1024
#define LL 4
#define HH 8
#define BB 2
#define TT 2048
#define VV 32000
#define SCALE_QK 0.08838834764831845f

typedef __bf16 bf16x8 __attribute__((ext_vector_type(8)));
typedef __bf16 bf16x4 __attribute__((ext_vector_type(4)));
typedef float  f32x4  __attribute__((ext_vector_type(4)));

__device__ __forceinline__ void gload_lds16(const void* g, void* l) {
  __builtin_amdgcn_global_load_lds((const __attribute__((address_space(1))) void*)g,
                                   (__attribute__((address_space(3))) void*)l, 16, 0, 0);
}

// =====================================================================
// gemm_mt: 256(M)x128(N), BK=32, 16x16x32 MFMA, ring3, 2 blocks/CU,
// counted vmcnt(6), ONE barrier per K-tile, XCD-chunked M-band decode
// (4-row bands when 4|nby — r14, FETCH-verified; 2-row when 2|nby).
// r15: wout reverted to MODE 2 (r14 split regressed: +reduction traffic
// on an 8.6 GF GEMM with shallow K); ff2 stays MODE 7 (r13-proven, -80us).
// MODE 0: bf16 ; 1: f32 ; 2: f32 acc+bias+res ; 3: bf16 lrelu(acc+bias) ;
// MODE 4: f32 acc+bias ; 5: f32 atomicAdd (split-K, z=(kc<<4)|bh) ;
// MODE 7: split-K PARTIALS — plain f32 to Cv + kc*cSB (no atomics).
// =====================================================================
template<int MODE>
__global__ __launch_bounds__(256, 2)
void gemm_mt(const __bf16* __restrict__ A, long ldA, long aSB, long aSH,
             const __bf16* __restrict__ Bt, long ldB, long bSB, long bSH,
             void* __restrict__ Cv, long ldC, long cSB, long cSH,
             const float* __restrict__ bias,
             const float* __restrict__ res, long ldR,
             int K)
{
  extern __shared__ __attribute__((aligned(16))) char smem[];

  int zbh = blockIdx.z;
  int kc = 0;
  if (MODE == 5) { kc = zbh >> 4; zbh &= 15; }
  if (MODE == 7) { kc = zbh; zbh = 0; }
  if (MODE == 5 || MODE == 7) {
    A  += (size_t)kc * K;
    Bt += (size_t)kc * K;
  }
  const int zb = zbh >> 3, zh = zbh & 7;
  A  += (size_t)zb * aSB + (size_t)zh * aSH;
  Bt += (size_t)zb * bSB + (size_t)zh * bSH;
  const size_t cOff = (MODE == 7) ? (size_t)kc * cSB
                                  : (size_t)zb * cSB + (size_t)zh * cSH;

  // XCD-chunked bijective swizzle, then M-band decode (r10/r14).
  const int nbx = gridDim.x, nby = gridDim.y;
  const int nwg = nbx * nby;
  const int fid = blockIdx.y * nbx + blockIdx.x;
  const int q8 = nwg >> 3, r8 = nwg & 7;
  const int xcd = fid & 7, idx = fid >> 3;
  const int swz = (xcd < r8 ? xcd * (q8 + 1) : r8 * (q8 + 1) + (xcd - r8) * q8) + idx;
  int bx, by;
  if ((nby & 3) == 0) {
    const int W = 4 * nbx;
    const int grp = swz / W, t = swz - grp * W;
    bx = t >> 2; by = grp * 4 + (t & 3);
  } else if ((nby & 1) == 0) {
    const int W = 2 * nbx;
    const int grp = swz / W, t = swz - grp * W;
    bx = t >> 1; by = grp * 2 + (t & 1);
  } else {
    bx = swz / nby; by = swz - bx * nby;
  }
  const int m0 = by * 256, n0 = bx * 128;

  const int tid = threadIdx.x;
  const int wv = tid >> 6, ln = tid & 63;
  const int wm = wv >> 1, wn = wv & 1;

  // A staging: wave wv covers rows [wv*64, wv*64+64), 4 granules/thread
  const int usA = (ln & 7) ^ (ln >> 3);
  const int rsA = wv * 64 + 2 * (ln >> 3) + (usA >> 2);
  const int ksA = (usA & 3) * 8;
  const __bf16* pA0 = A + (size_t)(m0 + rsA) * ldA + ksA;
  // B staging: all 256 threads cover 128 rows, 2 granules/thread
  const int usB = (tid & 7) ^ ((tid >> 3) & 7);
  const int rsB = 2 * (tid >> 3) + (usB >> 2);
  const int ksB = (usB & 3) * 8;
  const __bf16* pB0 = Bt + (size_t)(n0 + rsB) * ldB + ksB;

  // fragment read offsets (0-conflict scheme, measured r7)
  const int lr = ln & 15;
  const int gfr = ((((ln & 1) << 2) | ((ln >> 4) & 3)) ^ ((ln >> 1) & 7)) << 4;
  const int aR = (wm * 64 + (lr >> 1)) * 128 + gfr;            // + i*1024
  const int bR = 49152 + (wn * 32 + (lr >> 1)) * 128 + gfr;    // + j*1024

  f32x4 acc[8][4] = {};
  const int NT = K >> 5;

#define STG(sl) { \
    char* da = smem + (sl) * 16384 + wv * 4096 + ln * 16; \
    gload_lds16(pA0,            da); \
    gload_lds16(pA0 + 16 * ldA, da + 1024); \
    gload_lds16(pA0 + 32 * ldA, da + 2048); \
    gload_lds16(pA0 + 48 * ldA, da + 3072); \
    char* db = smem + 49152 + (sl) * 8192 + tid * 16; \
    gload_lds16(pB0,            db); \
    gload_lds16(pB0 + 64 * ldB, db + 4096); \
    pA0 += 32; pB0 += 32; }

  // prologue: stage units 0,1 (12 loads); wait unit0 (oldest 6)
  STG(0);
  if (NT > 1) {
    STG(1);
    asm volatile("s_waitcnt vmcnt(6)" ::: "memory");
  } else {
    asm volatile("s_waitcnt vmcnt(0)" ::: "memory");
  }
  __builtin_amdgcn_s_barrier();

  int sc = 0, sn = 1, sf = 2;
  for (int t = 0; t < NT; ++t) {
    if (t + 2 < NT) STG(sf);
    const char* aBase = smem + sc * 16384 + aR;
    const char* bBase = smem + sc * 8192 + bR;   // bR carries the 49152 base
    bf16x8 a[8], b[4];
#pragma unroll
    for (int j = 0; j < 4; j++) b[j] = *(const bf16x8*)(bBase + j * 1024);
#pragma unroll
    for (int i = 0; i < 8; i++) a[i] = *(const bf16x8*)(aBase + i * 1024);
    __builtin_amdgcn_s_setprio(1);
#pragma unroll
    for (int i = 0; i < 8; i++)
#pragma unroll
      for (int j = 0; j < 4; j++)
        acc[i][j] = __builtin_amdgcn_mfma_f32_16x16x32_bf16(a[i], b[j], acc[i][j], 0, 0, 0);
    __builtin_amdgcn_s_setprio(0);
    if (t + 1 < NT) {
      if (t + 2 < NT) { asm volatile("s_waitcnt vmcnt(6)" ::: "memory"); }
      else            { asm volatile("s_waitcnt vmcnt(0)" ::: "memory"); }
      __builtin_amdgcn_sched_barrier(0);
      __builtin_amdgcn_s_barrier();
    }
    const int tmp = sc; sc = sn; sn = sf; sf = tmp;
  }
#undef STG

  // epilogue (C/D mapping: col=lane&15, row=(lane>>4)*4+reg)
  const int rb = m0 + wm * 128 + (ln >> 4) * 4;
  const int cb = n0 + wn * 64 + lr;
#pragma unroll
  for (int i = 0; i < 8; i++)
#pragma unroll
    for (int j = 0; j < 4; j++) {
      const int col = cb + j * 16;
#pragma unroll
      for (int r = 0; r < 4; r++) {
        const int row = rb + i * 16 + r;
        float v = acc[i][j][r];
        const size_t ci = cOff + (size_t)row * ldC + col;
        if (MODE == 0)      ((__bf16*)Cv)[ci] = (__bf16)v;
        else if (MODE == 1) ((float*)Cv)[ci] = v;
        else if (MODE == 2) ((float*)Cv)[ci] = v + bias[col] + res[(size_t)row * ldR + col];
        else if (MODE == 3) { v += bias[col]; ((__bf16*)Cv)[ci] = (__bf16)(v >= 0.f ? v : 0.01f * v); }
        else if (MODE == 4) ((float*)Cv)[ci] = v + bias[col];
        else if (MODE == 5) atomicAdd(&((float*)Cv)[ci], v);
        else if (MODE == 7) ((float*)Cv)[ci] = v;
      }
    }
}

// ---------------- weight transpose + fp32->bf16 ----------------
__global__ void wtrans(const float* __restrict__ W, __bf16* __restrict__ Wt, int K, int N)
{
  const size_t zo = (size_t)blockIdx.z * K * N;
  __shared__ float t[32][33];
  const int n0 = blockIdx.x * 32, k0 = blockIdx.y * 32;
  const int tx = threadIdx.x, ty = threadIdx.y;
#pragma unroll
  for (int r = 0; r < 4; r++)
    t[ty + r * 8][tx] = W[zo + (size_t)(k0 + ty + r * 8) * N + n0 + tx];
  __syncthreads();
#pragma unroll
  for (int r = 0; r < 4; r++)
    Wt[zo + (size_t)(n0 + ty + r * 8) * K + k0 + tx] = (__bf16)t[tx][ty + r * 8];
}

// ---------------- V transpose per (b,h) ----------------
__global__ void vtrans(const __bf16* __restrict__ qkv, __bf16* __restrict__ Vt)
{
  const int z = blockIdx.z, bb = z >> 3, hh = z & 7;
  const __bf16* src = qkv + ((size_t)bb * TT + hh) * (3 * DD) + 2 * DD;
  __bf16* dst = Vt + (size_t)z * DD * 256;
  __shared__ __bf16 t[32][33];
  const int n0 = blockIdx.x * 32, i0 = blockIdx.y * 32;
  const int tx = threadIdx.x, ty = threadIdx.y;
#pragma unroll
  for (int r = 0; r < 4; r++)
    t[ty + r * 8][tx] = src[(size_t)(i0 + ty + r * 8) * (HH * 3 * DD) + n0 + tx];
  __syncthreads();
#pragma unroll
  for (int r = 0; r < 4; r++)
    dst[(size_t)(n0 + ty + r * 8) * 256 + i0 + tx] = t[tx][ty + r * 8];
}

// ---------------- embedding gather ----------------
__global__ void embed_k(const int* __restrict__ x, const float* __restrict__ emb, float* __restrict__ h)
{
  const int row = blockIdx.x;
  const int tok = x[row];
  ((float4*)(h + (size_t)row * DD))[threadIdx.x] = ((const float4*)(emb + (size_t)tok * DD))[threadIdx.x];
}

// ---------------- layernorm row -> bf16 ----------------
__global__ void ln_rows(const float* __restrict__ x, const float* __restrict__ g,
                        const float* __restrict__ b, __bf16* __restrict__ y)
{
  const int row = blockIdx.x, t = threadIdx.x;
  const int wv = t >> 6, ln = t & 63;
  const float4 v = ((const float4*)(x + (size_t)row * DD))[t];
  float s  = v.x + v.y + v.z + v.w;
  float ss = v.x * v.x + v.y * v.y + v.z * v.z + v.w * v.w;
#pragma unroll
  for (int o = 32; o; o >>= 1) { s += __shfl_xor(s, o); ss += __shfl_xor(ss, o); }
  __shared__ float rs_[4], rss_[4];
  if (!ln) { rs_[wv] = s; rss_[wv] = ss; }
  __syncthreads();
  s  = rs_[0] + rs_[1] + rs_[2] + rs_[3];
  ss = rss_[0] + rss_[1] + rss_[2] + rss_[3];
  const float mu  = s * (1.0f / DD);
  const float var = ss * (1.0f / DD) - mu * mu;
  const float r   = rsqrtf(var + 1e-5f);
  const float4 gv = ((const float4*)g)[t];
  const float4 bv = ((const float4*)b)[t];
  bf16x4 o = { (__bf16)((v.x - mu) * r * gv.x + bv.x),
               (__bf16)((v.y - mu) * r * gv.y + bv.y),
               (__bf16)((v.z - mu) * r * gv.z + bv.z),
               (__bf16)((v.w - mu) * r * gv.w + bv.w) };
  ((bf16x4*)(y + (size_t)row * DD))[t] = o;
}

// ---------------- h += sum(partials)+bias2, then layernorm -> bf16 ----------------
__global__ void ln_acc(float* __restrict__ h, const float* __restrict__ P, long pStride,
                       const float* __restrict__ bias2,
                       const float* __restrict__ g, const float* __restrict__ b,
                       __bf16* __restrict__ y)
{
  const int row = blockIdx.x, t = threadIdx.x;
  const int wv = t >> 6, ln = t & 63;
  float4 v = ((const float4*)(h + (size_t)row * DD))[t];
#pragma unroll
  for (int c = 0; c < 4; c++) {
    const float4 p = ((const float4*)(P + (size_t)c * pStride + (size_t)row * DD))[t];
    v.x += p.x; v.y += p.y; v.z += p.z; v.w += p.w;
  }
  const float4 b2 = ((const float4*)bias2)[t];
  v.x += b2.x; v.y += b2.y; v.z += b2.z; v.w += b2.w;
  ((float4*)(h + (size_t)row * DD))[t] = v;
  float s  = v.x + v.y + v.z + v.w;
  float ss = v.x * v.x + v.y * v.y + v.z * v.z + v.w * v.w;
#pragma unroll
  for (int o = 32; o; o >>= 1) { s += __shfl_xor(s, o); ss += __shfl_xor(ss, o); }
  __shared__ float rs_[4], rss_[4];
  if (!ln) { rs_[wv] = s; rss_[wv] = ss; }
  __syncthreads();
  s  = rs_[0] + rs_[1] + rs_[2] + rs_[3];
  ss = rss_[0] + rss_[1] + rss_[2] + rss_[3];
  const float mu  = s * (1.0f / DD);
  const float var = ss * (1.0f / DD) - mu * mu;
  const float r   = rsqrtf(var + 1e-5f);
  const float4 gv = ((const float4*)g)[t];
  const float4 bv = ((const float4*)b)[t];
  bf16x4 o = { (__bf16)((v.x - mu) * r * gv.x + bv.x),
               (__bf16)((v.y - mu) * r * gv.y + bv.y),
               (__bf16)((v.z - mu) * r * gv.z + bv.z),
               (__bf16)((v.w - mu) * r * gv.w + bv.w) };
  ((bf16x4*)(y + (size_t)row * DD))[t] = o;
}

// ---------------- h += sum(partials)+bias2, then fp32->bf16 ----------------
__global__ void f2bf_acc(const float* __restrict__ h, const float* __restrict__ P, long pStride,
                         const float* __restrict__ bias2, __bf16* __restrict__ y)
{
  const int row = blockIdx.x, t = threadIdx.x;
  float4 v = ((const float4*)(h + (size_t)row * DD))[t];
#pragma unroll
  for (int c = 0; c < 4; c++) {
    const float4 p = ((const float4*)(P + (size_t)c * pStride + (size_t)row * DD))[t];
    v.x += p.x; v.y += p.y; v.z += p.z; v.w += p.w;
  }
  const float4 b2 = ((const float4*)bias2)[t];
  bf16x4 o = { (__bf16)(v.x + b2.x), (__bf16)(v.y + b2.y),
               (__bf16)(v.z + b2.z), (__bf16)(v.w + b2.w) };
  ((bf16x4*)(y + (size_t)row * DD))[t] = o;
}

// ---------------- softmax over 256-wide rows -> bf16 ----------------
__global__ void softmax256(const float* __restrict__ S, __bf16* __restrict__ P)
{
  const int row = blockIdx.x, t = threadIdx.x;
  const int wv = t >> 6, ln = t & 63;
  const float v = S[(size_t)row * 256 + t] * SCALE_QK;
  float m = v;
#pragma unroll
  for (int o = 32; o; o >>= 1) m = fmaxf(m, __shfl_xor(m, o));
  __shared__ float red[8];
  if (!ln) red[wv] = m;
  __syncthreads();
  m = fmaxf(fmaxf(red[0], red[1]), fmaxf(red[2], red[3]));
  const float e = __expf(v - m);
  float s = e;
#pragma unroll
  for (int o = 32; o; o >>= 1) s += __shfl_xor(s, o);
  if (!ln) red[4 + wv] = s;
  __syncthreads();
  s = red[4] + red[5] + red[6] + red[7];
  P[(size_t)row * 256 + t] = (__bf16)(e / s);
}

template<int MODE>
static void G(const __bf16* A, long ldA, long aSB, long aSH,
              const __bf16* Bt, long ldB, long bSB, long bSH,
              void* C, long ldC, long cSB, long cSH,
              const float* bias, const float* res, long ldR,
              int M, int N, int K, int Z, hipStream_t s)
{
  hipFuncSetAttribute((const void*)gemm_mt<MODE>,
                      hipFuncAttributeMaxDynamicSharedMemorySize, 73728);
  gemm_mt<MODE><<<dim3(N / 128, M / 256, Z), 256, 73728, s>>>(
      A, ldA, aSB, aSH, Bt, ldB, bSB, bSH, C, ldC, cSB, cSH, bias, res, ldR, K);
}

extern "C" void kernel_launch(void* const* d_in, const int* in_sizes, int n_in,
                              void* d_out, int out_size, void* d_ws, size_t ws_size,
                              hipStream_t stream)
{
  const int*   x       = (const int*)  d_in[0];
  const float* emb     = (const float*)d_in[1];
  const float* ln1_g   = (const float*)d_in[2];
  const float* ln1_b   = (const float*)d_in[3];
  const float* wqkv    = (const float*)d_in[4];
  const float* wout_w  = (const float*)d_in[5];
  const float* wout_b  = (const float*)d_in[6];
  const float* ln2_g   = (const float*)d_in[7];
  const float* ln2_b   = (const float*)d_in[8];
  const float* ff1_w   = (const float*)d_in[9];
  const float* ff1_b   = (const float*)d_in[10];
  const float* ff2_w   = (const float*)d_in[11];
  const float* ff2_b   = (const float*)d_in[12];
  const float* logit_w = (const float*)d_in[13];
  const float* logit_b = (const float*)d_in[14];
  float* out = (float*)d_out;

  const int M = BB * TT;

  char* w = (char*)d_ws;
  size_t off = 0;
  auto take = [&](size_t bytes) { void* p = w + off; off += (bytes + 255) & ~(size_t)255; return p; };
  __bf16* wqkvT = (__bf16*)take((size_t)LL * 3 * DD * DD * 2);
  __bf16* woutT = (__bf16*)take((size_t)LL * DD * DD * 2);
  __bf16* ff1T  = (__bf16*)take((size_t)LL * 4 * DD * DD * 2);
  __bf16* ff2T  = (__bf16*)take((size_t)LL * DD * 4 * DD * 2);
  __bf16* logT  = (__bf16*)take((size_t)VV * DD * 2);
  float*  h     = (float*) take((size_t)M * DD * 4);
  __bf16* ybf   = (__bf16*)take((size_t)M * DD * 2);
  __bf16* qkvbf = (__bf16*)take((size_t)M * 3 * DD * 2);
  float*  Smat  = (float*) take((size_t)BB * HH * 256 * 256 * 4);
  __bf16* Pbf   = (__bf16*)take((size_t)BB * HH * 256 * 256 * 2);
  __bf16* Vt    = (__bf16*)take((size_t)BB * HH * DD * 256 * 2);
  __bf16* Obf   = (__bf16*)take((size_t)M * DD * 2);
  __bf16* midbf = (__bf16*)take((size_t)M * 4 * DD * 2);
  float*  part  = (float*) take((size_t)4 * M * DD * 4);   // ff2 split-K partials
  if (ws_size < off) return;

  const dim3 tb(32, 8);
  wtrans<<<dim3(3 * DD / 32, DD / 32, LL), tb, 0, stream>>>(wqkv,   wqkvT, DD, 3 * DD);
  wtrans<<<dim3(DD / 32,     DD / 32, LL), tb, 0, stream>>>(wout_w, woutT, DD, DD);
  wtrans<<<dim3(4 * DD / 32, DD / 32, LL), tb, 0, stream>>>(ff1_w,  ff1T,  DD, 4 * DD);
  wtrans<<<dim3(DD / 32, 4 * DD / 32, LL), tb, 0, stream>>>(ff2_w,  ff2T,  4 * DD, DD);
  wtrans<<<dim3(VV / 32,     DD / 32, 1),  tb, 0, stream>>>(logit_w, logT, DD, VV);

  embed_k<<<M, 256, 0, stream>>>(x, emb, h);

  for (int l = 0; l < LL; l++) {
    // ln1 (fused with ff2(l-1) partial reduction + residual for l>0)
    if (l == 0)
      ln_rows<<<M, 256, 0, stream>>>(h, ln1_g, ln1_b, ybf);
    else
      ln_acc<<<M, 256, 0, stream>>>(h, part, (long)M * DD, ff2_b + (size_t)(l - 1) * DD,
                                    ln1_g + (size_t)l * DD, ln1_b + (size_t)l * DD, ybf);
    // qkv = y @ wqkv
    G<0>(ybf, DD, 0, 0, wqkvT + (size_t)l * 3 * DD * DD, DD, 0, 0,
         qkvbf, 3 * DD, 0, 0, nullptr, nullptr, 0, M, 3 * DD, DD, 1, stream);
    // S = Q @ K^T  (split-K x8, atomic accumulate into zeroed Smat -> 256 blocks)
    hipMemsetAsync(Smat, 0, (size_t)BB * HH * 256 * 256 * 4, stream);
    G<5>(qkvbf, HH * 3 * DD, (long)TT * 3 * DD, 3 * DD,
         qkvbf + DD, HH * 3 * DD, (long)TT * 3 * DD, 3 * DD,
         Smat, 256, (long)HH * 256 * 256, 256 * 256,
         nullptr, nullptr, 0, 256, 256, DD / 8, 8 * BB * HH, stream);
    softmax256<<<BB * HH * 256, 256, 0, stream>>>(Smat, Pbf);
    vtrans<<<dim3(DD / 32, 256 / 32, BB * HH), tb, 0, stream>>>(qkvbf, Vt);
    // O = P @ V
    G<0>(Pbf, 256, (long)HH * 256 * 256, 256 * 256,
         Vt, 256, (long)HH * DD * 256, (long)DD * 256,
         Obf, HH * DD, (long)TT * DD, DD,
         nullptr, nullptr, 0, 256, DD, 256, BB * HH, stream);
    // h += O @ wout + b   (MODE 2, r13-proven)
    G<2>(Obf, DD, 0, 0, woutT + (size_t)l * DD * DD, DD, 0, 0,
         h, DD, 0, 0, wout_b + (size_t)l * DD, h, DD, M, DD, DD, 1, stream);
    ln_rows<<<M, 256, 0, stream>>>(h, ln2_g + (size_t)l * DD, ln2_b + (size_t)l * DD, ybf);
    // mid = lrelu(y @ ff1 + b1)
    G<3>(ybf, DD, 0, 0, ff1T + (size_t)l * 4 * DD * DD, DD, 0, 0,
         midbf, 4 * DD, 0, 0, ff1_b + (size_t)l * 4 * DD, nullptr, 0, M, 4 * DD, DD, 1, stream);
    // ff2 partials: part[kc] = mid[:, kc*1024:(kc+1)*1024] @ ff2[kc-chunk]  (512 blocks)
    G<7>(midbf, 4 * DD, 0, 0, ff2T + (size_t)l * DD * 4 * DD, 4 * DD, 0, 0,
         part, DD, (long)M * DD, 0, nullptr, nullptr, 0, M, DD, DD, 4, stream);
  }

  // final: h += sum(partials)+b2(layer3), convert to bf16
  f2bf_acc<<<M, 256, 0, stream>>>(h, part, (long)M * DD, ff2_b + (size_t)3 * DD, ybf);
  // logits = h @ logit_w + logit_b
  G<4>(ybf, DD, 0, 0, logT, DD, 0, 0,
       out, VV, 0, 0, logit_b, nullptr, 0, M, VV, DD, 1, stream);
}

// Round 16
// 1325.851 us; speedup vs baseline: 1.0193x; 1.0193x over previous
//
#include <hip/hip_runtime.h>

#define DD 1024
#define LL 4
#define HH 8
#define BB 2
#define TT 2048
#define VV 32000
#define SCALE_QK 0.08838834764831845f

typedef __bf16 bf16x8 __attribute__((ext_vector_type(8)));
typedef __bf16 bf16x4 __attribute__((ext_vector_type(4)));
typedef float  f32x4  __attribute__((ext_vector_type(4)));

__device__ __forceinline__ void gload_lds16(const void* g, void* l) {
  __builtin_amdgcn_global_load_lds((const __attribute__((address_space(1))) void*)g,
                                   (__attribute__((address_space(3))) void*)l, 16, 0, 0);
}

// =====================================================================
// gemm_mt: 256(M)x128(N), BK=32, 16x16x32 MFMA, ring3, 2 blocks/CU,
// counted vmcnt(6), ONE barrier per K-tile, XCD-chunked 2-row M-band
// decode (r10/r13 config; r15's QK-x8 + 4-row band decomposed to +51us
// and is reverted). wout and ff2 both use MODE 7 split-K partials with
// reductions fused into ln_acc/f2bf_acc (r13+r14 factor analysis).
// MODE 0: bf16 ; 1: f32 ; 2: f32 acc+bias+res ; 3: bf16 lrelu(acc+bias) ;
// MODE 4: f32 acc+bias ; 5: f32 atomicAdd (split-K, z=(kc<<4)|bh) ;
// MODE 7: split-K PARTIALS — plain f32 to Cv + kc*cSB (no atomics).
// =====================================================================
template<int MODE>
__global__ __launch_bounds__(256, 2)
void gemm_mt(const __bf16* __restrict__ A, long ldA, long aSB, long aSH,
             const __bf16* __restrict__ Bt, long ldB, long bSB, long bSH,
             void* __restrict__ Cv, long ldC, long cSB, long cSH,
             const float* __restrict__ bias,
             const float* __restrict__ res, long ldR,
             int K)
{
  extern __shared__ __attribute__((aligned(16))) char smem[];

  int zbh = blockIdx.z;
  int kc = 0;
  if (MODE == 5) { kc = zbh >> 4; zbh &= 15; }
  if (MODE == 7) { kc = zbh; zbh = 0; }
  if (MODE == 5 || MODE == 7) {
    A  += (size_t)kc * K;
    Bt += (size_t)kc * K;
  }
  const int zb = zbh >> 3, zh = zbh & 7;
  A  += (size_t)zb * aSB + (size_t)zh * aSH;
  Bt += (size_t)zb * bSB + (size_t)zh * bSH;
  const size_t cOff = (MODE == 7) ? (size_t)kc * cSB
                                  : (size_t)zb * cSB + (size_t)zh * cSH;

  // XCD-chunked bijective swizzle, then 2-row M-band decode (r10).
  const int nbx = gridDim.x, nby = gridDim.y;
  const int nwg = nbx * nby;
  const int fid = blockIdx.y * nbx + blockIdx.x;
  const int q8 = nwg >> 3, r8 = nwg & 7;
  const int xcd = fid & 7, idx = fid >> 3;
  const int swz = (xcd < r8 ? xcd * (q8 + 1) : r8 * (q8 + 1) + (xcd - r8) * q8) + idx;
  int bx, by;
  if ((nby & 1) == 0) {
    const int W = 2 * nbx;
    const int grp = swz / W, t = swz - grp * W;
    bx = t >> 1; by = grp * 2 + (t & 1);
  } else {
    bx = swz / nby; by = swz - bx * nby;
  }
  const int m0 = by * 256, n0 = bx * 128;

  const int tid = threadIdx.x;
  const int wv = tid >> 6, ln = tid & 63;
  const int wm = wv >> 1, wn = wv & 1;

  // A staging: wave wv covers rows [wv*64, wv*64+64), 4 granules/thread
  const int usA = (ln & 7) ^ (ln >> 3);
  const int rsA = wv * 64 + 2 * (ln >> 3) + (usA >> 2);
  const int ksA = (usA & 3) * 8;
  const __bf16* pA0 = A + (size_t)(m0 + rsA) * ldA + ksA;
  // B staging: all 256 threads cover 128 rows, 2 granules/thread
  const int usB = (tid & 7) ^ ((tid >> 3) & 7);
  const int rsB = 2 * (tid >> 3) + (usB >> 2);
  const int ksB = (usB & 3) * 8;
  const __bf16* pB0 = Bt + (size_t)(n0 + rsB) * ldB + ksB;

  // fragment read offsets (0-conflict scheme, measured r7)
  const int lr = ln & 15;
  const int gfr = ((((ln & 1) << 2) | ((ln >> 4) & 3)) ^ ((ln >> 1) & 7)) << 4;
  const int aR = (wm * 64 + (lr >> 1)) * 128 + gfr;            // + i*1024
  const int bR = 49152 + (wn * 32 + (lr >> 1)) * 128 + gfr;    // + j*1024

  f32x4 acc[8][4] = {};
  const int NT = K >> 5;

#define STG(sl) { \
    char* da = smem + (sl) * 16384 + wv * 4096 + ln * 16; \
    gload_lds16(pA0,            da); \
    gload_lds16(pA0 + 16 * ldA, da + 1024); \
    gload_lds16(pA0 + 32 * ldA, da + 2048); \
    gload_lds16(pA0 + 48 * ldA, da + 3072); \
    char* db = smem + 49152 + (sl) * 8192 + tid * 16; \
    gload_lds16(pB0,            db); \
    gload_lds16(pB0 + 64 * ldB, db + 4096); \
    pA0 += 32; pB0 += 32; }

  // prologue: stage units 0,1 (12 loads); wait unit0 (oldest 6)
  STG(0);
  if (NT > 1) {
    STG(1);
    asm volatile("s_waitcnt vmcnt(6)" ::: "memory");
  } else {
    asm volatile("s_waitcnt vmcnt(0)" ::: "memory");
  }
  __builtin_amdgcn_s_barrier();

  int sc = 0, sn = 1, sf = 2;
  for (int t = 0; t < NT; ++t) {
    if (t + 2 < NT) STG(sf);
    const char* aBase = smem + sc * 16384 + aR;
    const char* bBase = smem + sc * 8192 + bR;   // bR carries the 49152 base
    bf16x8 a[8], b[4];
#pragma unroll
    for (int j = 0; j < 4; j++) b[j] = *(const bf16x8*)(bBase + j * 1024);
#pragma unroll
    for (int i = 0; i < 8; i++) a[i] = *(const bf16x8*)(aBase + i * 1024);
    __builtin_amdgcn_s_setprio(1);
#pragma unroll
    for (int i = 0; i < 8; i++)
#pragma unroll
      for (int j = 0; j < 4; j++)
        acc[i][j] = __builtin_amdgcn_mfma_f32_16x16x32_bf16(a[i], b[j], acc[i][j], 0, 0, 0);
    __builtin_amdgcn_s_setprio(0);
    if (t + 1 < NT) {
      if (t + 2 < NT) { asm volatile("s_waitcnt vmcnt(6)" ::: "memory"); }
      else            { asm volatile("s_waitcnt vmcnt(0)" ::: "memory"); }
      __builtin_amdgcn_sched_barrier(0);
      __builtin_amdgcn_s_barrier();
    }
    const int tmp = sc; sc = sn; sn = sf; sf = tmp;
  }
#undef STG

  // epilogue (C/D mapping: col=lane&15, row=(lane>>4)*4+reg)
  const int rb = m0 + wm * 128 + (ln >> 4) * 4;
  const int cb = n0 + wn * 64 + lr;
#pragma unroll
  for (int i = 0; i < 8; i++)
#pragma unroll
    for (int j = 0; j < 4; j++) {
      const int col = cb + j * 16;
#pragma unroll
      for (int r = 0; r < 4; r++) {
        const int row = rb + i * 16 + r;
        float v = acc[i][j][r];
        const size_t ci = cOff + (size_t)row * ldC + col;
        if (MODE == 0)      ((__bf16*)Cv)[ci] = (__bf16)v;
        else if (MODE == 1) ((float*)Cv)[ci] = v;
        else if (MODE == 2) ((float*)Cv)[ci] = v + bias[col] + res[(size_t)row * ldR + col];
        else if (MODE == 3) { v += bias[col]; ((__bf16*)Cv)[ci] = (__bf16)(v >= 0.f ? v : 0.01f * v); }
        else if (MODE == 4) ((float*)Cv)[ci] = v + bias[col];
        else if (MODE == 5) atomicAdd(&((float*)Cv)[ci], v);
        else if (MODE == 7) ((float*)Cv)[ci] = v;
      }
    }
}

// ---------------- weight transpose + fp32->bf16 ----------------
__global__ void wtrans(const float* __restrict__ W, __bf16* __restrict__ Wt, int K, int N)
{
  const size_t zo = (size_t)blockIdx.z * K * N;
  __shared__ float t[32][33];
  const int n0 = blockIdx.x * 32, k0 = blockIdx.y * 32;
  const int tx = threadIdx.x, ty = threadIdx.y;
#pragma unroll
  for (int r = 0; r < 4; r++)
    t[ty + r * 8][tx] = W[zo + (size_t)(k0 + ty + r * 8) * N + n0 + tx];
  __syncthreads();
#pragma unroll
  for (int r = 0; r < 4; r++)
    Wt[zo + (size_t)(n0 + ty + r * 8) * K + k0 + tx] = (__bf16)t[tx][ty + r * 8];
}

// ---------------- V transpose per (b,h) ----------------
__global__ void vtrans(const __bf16* __restrict__ qkv, __bf16* __restrict__ Vt)
{
  const int z = blockIdx.z, bb = z >> 3, hh = z & 7;
  const __bf16* src = qkv + ((size_t)bb * TT + hh) * (3 * DD) + 2 * DD;
  __bf16* dst = Vt + (size_t)z * DD * 256;
  __shared__ __bf16 t[32][33];
  const int n0 = blockIdx.x * 32, i0 = blockIdx.y * 32;
  const int tx = threadIdx.x, ty = threadIdx.y;
#pragma unroll
  for (int r = 0; r < 4; r++)
    t[ty + r * 8][tx] = src[(size_t)(i0 + ty + r * 8) * (HH * 3 * DD) + n0 + tx];
  __syncthreads();
#pragma unroll
  for (int r = 0; r < 4; r++)
    dst[(size_t)(n0 + ty + r * 8) * 256 + i0 + tx] = t[tx][ty + r * 8];
}

// ---------------- embedding gather ----------------
__global__ void embed_k(const int* __restrict__ x, const float* __restrict__ emb, float* __restrict__ h)
{
  const int row = blockIdx.x;
  const int tok = x[row];
  ((float4*)(h + (size_t)row * DD))[threadIdx.x] = ((const float4*)(emb + (size_t)tok * DD))[threadIdx.x];
}

// ---------------- layernorm row -> bf16 ----------------
__global__ void ln_rows(const float* __restrict__ x, const float* __restrict__ g,
                        const float* __restrict__ b, __bf16* __restrict__ y)
{
  const int row = blockIdx.x, t = threadIdx.x;
  const int wv = t >> 6, ln = t & 63;
  const float4 v = ((const float4*)(x + (size_t)row * DD))[t];
  float s  = v.x + v.y + v.z + v.w;
  float ss = v.x * v.x + v.y * v.y + v.z * v.z + v.w * v.w;
#pragma unroll
  for (int o = 32; o; o >>= 1) { s += __shfl_xor(s, o); ss += __shfl_xor(ss, o); }
  __shared__ float rs_[4], rss_[4];
  if (!ln) { rs_[wv] = s; rss_[wv] = ss; }
  __syncthreads();
  s  = rs_[0] + rs_[1] + rs_[2] + rs_[3];
  ss = rss_[0] + rss_[1] + rss_[2] + rss_[3];
  const float mu  = s * (1.0f / DD);
  const float var = ss * (1.0f / DD) - mu * mu;
  const float r   = rsqrtf(var + 1e-5f);
  const float4 gv = ((const float4*)g)[t];
  const float4 bv = ((const float4*)b)[t];
  bf16x4 o = { (__bf16)((v.x - mu) * r * gv.x + bv.x),
               (__bf16)((v.y - mu) * r * gv.y + bv.y),
               (__bf16)((v.z - mu) * r * gv.z + bv.z),
               (__bf16)((v.w - mu) * r * gv.w + bv.w) };
  ((bf16x4*)(y + (size_t)row * DD))[t] = o;
}

// ---------------- h += sum(partials)+bias2, then layernorm -> bf16 ----------------
__global__ void ln_acc(float* __restrict__ h, const float* __restrict__ P, long pStride,
                       const float* __restrict__ bias2,
                       const float* __restrict__ g, const float* __restrict__ b,
                       __bf16* __restrict__ y)
{
  const int row = blockIdx.x, t = threadIdx.x;
  const int wv = t >> 6, ln = t & 63;
  float4 v = ((const float4*)(h + (size_t)row * DD))[t];
#pragma unroll
  for (int c = 0; c < 4; c++) {
    const float4 p = ((const float4*)(P + (size_t)c * pStride + (size_t)row * DD))[t];
    v.x += p.x; v.y += p.y; v.z += p.z; v.w += p.w;
  }
  const float4 b2 = ((const float4*)bias2)[t];
  v.x += b2.x; v.y += b2.y; v.z += b2.z; v.w += b2.w;
  ((float4*)(h + (size_t)row * DD))[t] = v;
  float s  = v.x + v.y + v.z + v.w;
  float ss = v.x * v.x + v.y * v.y + v.z * v.z + v.w * v.w;
#pragma unroll
  for (int o = 32; o; o >>= 1) { s += __shfl_xor(s, o); ss += __shfl_xor(ss, o); }
  __shared__ float rs_[4], rss_[4];
  if (!ln) { rs_[wv] = s; rss_[wv] = ss; }
  __syncthreads();
  s  = rs_[0] + rs_[1] + rs_[2] + rs_[3];
  ss = rss_[0] + rss_[1] + rss_[2] + rss_[3];
  const float mu  = s * (1.0f / DD);
  const float var = ss * (1.0f / DD) - mu * mu;
  const float r   = rsqrtf(var + 1e-5f);
  const float4 gv = ((const float4*)g)[t];
  const float4 bv = ((const float4*)b)[t];
  bf16x4 o = { (__bf16)((v.x - mu) * r * gv.x + bv.x),
               (__bf16)((v.y - mu) * r * gv.y + bv.y),
               (__bf16)((v.z - mu) * r * gv.z + bv.z),
               (__bf16)((v.w - mu) * r * gv.w + bv.w) };
  ((bf16x4*)(y + (size_t)row * DD))[t] = o;
}

// ---------------- h += sum(partials)+bias2, then fp32->bf16 ----------------
__global__ void f2bf_acc(const float* __restrict__ h, const float* __restrict__ P, long pStride,
                         const float* __restrict__ bias2, __bf16* __restrict__ y)
{
  const int row = blockIdx.x, t = threadIdx.x;
  float4 v = ((const float4*)(h + (size_t)row * DD))[t];
#pragma unroll
  for (int c = 0; c < 4; c++) {
    const float4 p = ((const float4*)(P + (size_t)c * pStride + (size_t)row * DD))[t];
    v.x += p.x; v.y += p.y; v.z += p.z; v.w += p.w;
  }
  const float4 b2 = ((const float4*)bias2)[t];
  bf16x4 o = { (__bf16)(v.x + b2.x), (__bf16)(v.y + b2.y),
               (__bf16)(v.z + b2.z), (__bf16)(v.w + b2.w) };
  ((bf16x4*)(y + (size_t)row * DD))[t] = o;
}

// ---------------- softmax over 256-wide rows -> bf16 ----------------
__global__ void softmax256(const float* __restrict__ S, __bf16* __restrict__ P)
{
  const int row = blockIdx.x, t = threadIdx.x;
  const int wv = t >> 6, ln = t & 63;
  const float v = S[(size_t)row * 256 + t] * SCALE_QK;
  float m = v;
#pragma unroll
  for (int o = 32; o; o >>= 1) m = fmaxf(m, __shfl_xor(m, o));
  __shared__ float red[8];
  if (!ln) red[wv] = m;
  __syncthreads();
  m = fmaxf(fmaxf(red[0], red[1]), fmaxf(red[2], red[3]));
  const float e = __expf(v - m);
  float s = e;
#pragma unroll
  for (int o = 32; o; o >>= 1) s += __shfl_xor(s, o);
  if (!ln) red[4 + wv] = s;
  __syncthreads();
  s = red[4] + red[5] + red[6] + red[7];
  P[(size_t)row * 256 + t] = (__bf16)(e / s);
}

template<int MODE>
static void G(const __bf16* A, long ldA, long aSB, long aSH,
              const __bf16* Bt, long ldB, long bSB, long bSH,
              void* C, long ldC, long cSB, long cSH,
              const float* bias, const float* res, long ldR,
              int M, int N, int K, int Z, hipStream_t s)
{
  hipFuncSetAttribute((const void*)gemm_mt<MODE>,
                      hipFuncAttributeMaxDynamicSharedMemorySize, 73728);
  gemm_mt<MODE><<<dim3(N / 128, M / 256, Z), 256, 73728, s>>>(
      A, ldA, aSB, aSH, Bt, ldB, bSB, bSH, C, ldC, cSB, cSH, bias, res, ldR, K);
}

extern "C" void kernel_launch(void* const* d_in, const int* in_sizes, int n_in,
                              void* d_out, int out_size, void* d_ws, size_t ws_size,
                              hipStream_t stream)
{
  const int*   x       = (const int*)  d_in[0];
  const float* emb     = (const float*)d_in[1];
  const float* ln1_g   = (const float*)d_in[2];
  const float* ln1_b   = (const float*)d_in[3];
  const float* wqkv    = (const float*)d_in[4];
  const float* wout_w  = (const float*)d_in[5];
  const float* wout_b  = (const float*)d_in[6];
  const float* ln2_g   = (const float*)d_in[7];
  const float* ln2_b   = (const float*)d_in[8];
  const float* ff1_w   = (const float*)d_in[9];
  const float* ff1_b   = (const float*)d_in[10];
  const float* ff2_w   = (const float*)d_in[11];
  const float* ff2_b   = (const float*)d_in[12];
  const float* logit_w = (const float*)d_in[13];
  const float* logit_b = (const float*)d_in[14];
  float* out = (float*)d_out;

  const int M = BB * TT;

  char* w = (char*)d_ws;
  size_t off = 0;
  auto take = [&](size_t bytes) { void* p = w + off; off += (bytes + 255) & ~(size_t)255; return p; };
  __bf16* wqkvT = (__bf16*)take((size_t)LL * 3 * DD * DD * 2);
  __bf16* woutT = (__bf16*)take((size_t)LL * DD * DD * 2);
  __bf16* ff1T  = (__bf16*)take((size_t)LL * 4 * DD * DD * 2);
  __bf16* ff2T  = (__bf16*)take((size_t)LL * DD * 4 * DD * 2);
  __bf16* logT  = (__bf16*)take((size_t)VV * DD * 2);
  float*  h     = (float*) take((size_t)M * DD * 4);
  __bf16* ybf   = (__bf16*)take((size_t)M * DD * 2);
  __bf16* qkvbf = (__bf16*)take((size_t)M * 3 * DD * 2);
  float*  Smat  = (float*) take((size_t)BB * HH * 256 * 256 * 4);
  __bf16* Pbf   = (__bf16*)take((size_t)BB * HH * 256 * 256 * 2);
  __bf16* Vt    = (__bf16*)take((size_t)BB * HH * DD * 256 * 2);
  __bf16* Obf   = (__bf16*)take((size_t)M * DD * 2);
  __bf16* midbf = (__bf16*)take((size_t)M * 4 * DD * 2);
  float*  part  = (float*) take((size_t)4 * M * DD * 4);   // split-K partials (wout & ff2, sequential)
  if (ws_size < off) return;

  const dim3 tb(32, 8);
  wtrans<<<dim3(3 * DD / 32, DD / 32, LL), tb, 0, stream>>>(wqkv,   wqkvT, DD, 3 * DD);
  wtrans<<<dim3(DD / 32,     DD / 32, LL), tb, 0, stream>>>(wout_w, woutT, DD, DD);
  wtrans<<<dim3(4 * DD / 32, DD / 32, LL), tb, 0, stream>>>(ff1_w,  ff1T,  DD, 4 * DD);
  wtrans<<<dim3(DD / 32, 4 * DD / 32, LL), tb, 0, stream>>>(ff2_w,  ff2T,  4 * DD, DD);
  wtrans<<<dim3(VV / 32,     DD / 32, 1),  tb, 0, stream>>>(logit_w, logT, DD, VV);

  embed_k<<<M, 256, 0, stream>>>(x, emb, h);

  for (int l = 0; l < LL; l++) {
    // ln1 (fused with ff2(l-1) partial reduction + residual for l>0)
    if (l == 0)
      ln_rows<<<M, 256, 0, stream>>>(h, ln1_g, ln1_b, ybf);
    else
      ln_acc<<<M, 256, 0, stream>>>(h, part, (long)M * DD, ff2_b + (size_t)(l - 1) * DD,
                                    ln1_g + (size_t)l * DD, ln1_b + (size_t)l * DD, ybf);
    // qkv = y @ wqkv
    G<0>(ybf, DD, 0, 0, wqkvT + (size_t)l * 3 * DD * DD, DD, 0, 0,
         qkvbf, 3 * DD, 0, 0, nullptr, nullptr, 0, M, 3 * DD, DD, 1, stream);
    // S = Q @ K^T  (split-K x4, atomic accumulate into zeroed Smat — r10/r13 proven)
    hipMemsetAsync(Smat, 0, (size_t)BB * HH * 256 * 256 * 4, stream);
    G<5>(qkvbf, HH * 3 * DD, (long)TT * 3 * DD, 3 * DD,
         qkvbf + DD, HH * 3 * DD, (long)TT * 3 * DD, 3 * DD,
         Smat, 256, (long)HH * 256 * 256, 256 * 256,
         nullptr, nullptr, 0, 256, 256, DD / 4, 4 * BB * HH, stream);
    softmax256<<<BB * HH * 256, 256, 0, stream>>>(Smat, Pbf);
    vtrans<<<dim3(DD / 32, 256 / 32, BB * HH), tb, 0, stream>>>(qkvbf, Vt);
    // O = P @ V
    G<0>(Pbf, 256, (long)HH * 256 * 256, 256 * 256,
         Vt, 256, (long)HH * DD * 256, (long)DD * 256,
         Obf, HH * DD, (long)TT * DD, DD,
         nullptr, nullptr, 0, 256, DD, 256, BB * HH, stream);
    // wout partials (512 blocks, no atomics)
    G<7>(Obf, DD, 0, 0, woutT + (size_t)l * DD * DD, DD, 0, 0,
         part, DD, (long)M * DD, 0, nullptr, nullptr, 0, M, DD, DD / 4, 4, stream);
    // ln2 fused with wout reduction + residual
    ln_acc<<<M, 256, 0, stream>>>(h, part, (long)M * DD, wout_b + (size_t)l * DD,
                                  ln2_g + (size_t)l * DD, ln2_b + (size_t)l * DD, ybf);
    // mid = lrelu(y @ ff1 + b1)
    G<3>(ybf, DD, 0, 0, ff1T + (size_t)l * 4 * DD * DD, DD, 0, 0,
         midbf, 4 * DD, 0, 0, ff1_b + (size_t)l * 4 * DD, nullptr, 0, M, 4 * DD, DD, 1, stream);
    // ff2 partials (512 blocks, no atomics)
    G<7>(midbf, 4 * DD, 0, 0, ff2T + (size_t)l * DD * 4 * DD, 4 * DD, 0, 0,
         part, DD, (long)M * DD, 0, nullptr, nullptr, 0, M, DD, DD, 4, stream);
  }

  // final: h += sum(partials)+b2(layer3), convert to bf16
  f2bf_acc<<<M, 256, 0, stream>>>(h, part, (long)M * DD, ff2_b + (size_t)3 * DD, ybf);
  // logits = h @ logit_w + logit_b
  G<4>(ybf, DD, 0, 0, logT, DD, 0, 0,
       out, VV, 0, 0, logit_b, nullptr, 0, M, VV, DD, 1, stream);
}

// Round 17
// 1303.271 us; speedup vs baseline: 1.0369x; 1.0173x over previous
//
#include <hip/hip_runtime.h>

#define DD 1024
#define LL 4
#define HH 8
#define BB 2
#define TT 2048
#define VV 32000
#define SCALE_QK 0.08838834764831845f

typedef __bf16 bf16x8 __attribute__((ext_vector_type(8)));
typedef __bf16 bf16x4 __attribute__((ext_vector_type(4)));
typedef float  f32x4  __attribute__((ext_vector_type(4)));

__device__ __forceinline__ void gload_lds16(const void* g, void* l) {
  __builtin_amdgcn_global_load_lds((const __attribute__((address_space(1))) void*)g,
                                   (__attribute__((address_space(3))) void*)l, 16, 0, 0);
}

// =====================================================================
// gemm_mt (r13 configuration — best measured, 1300us):
// 256(M)x128(N), BK=32, 16x16x32 MFMA, ring3, 2 blocks/CU, counted
// vmcnt(6), ONE barrier per K-tile, XCD-chunked 2-row M-band decode.
// ff2 uses MODE 7 split-K partials (reduction fused into ln_acc/f2bf_acc);
// wout stays MODE 2; QK split-K x4 via MODE 5 atomics.
// MODE 0: bf16 ; 1: f32 ; 2: f32 acc+bias+res ; 3: bf16 lrelu(acc+bias) ;
// MODE 4: f32 acc+bias ; 5: f32 atomicAdd (split-K, z=(kc<<4)|bh) ;
// MODE 7: split-K PARTIALS — plain f32 to Cv + kc*cSB (no atomics).
// =====================================================================
template<int MODE>
__global__ __launch_bounds__(256, 2)
void gemm_mt(const __bf16* __restrict__ A, long ldA, long aSB, long aSH,
             const __bf16* __restrict__ Bt, long ldB, long bSB, long bSH,
             void* __restrict__ Cv, long ldC, long cSB, long cSH,
             const float* __restrict__ bias,
             const float* __restrict__ res, long ldR,
             int K)
{
  extern __shared__ __attribute__((aligned(16))) char smem[];

  int zbh = blockIdx.z;
  int kc = 0;
  if (MODE == 5) { kc = zbh >> 4; zbh &= 15; }
  if (MODE == 7) { kc = zbh; zbh = 0; }
  if (MODE == 5 || MODE == 7) {
    A  += (size_t)kc * K;
    Bt += (size_t)kc * K;
  }
  const int zb = zbh >> 3, zh = zbh & 7;
  A  += (size_t)zb * aSB + (size_t)zh * aSH;
  Bt += (size_t)zb * bSB + (size_t)zh * bSH;
  const size_t cOff = (MODE == 7) ? (size_t)kc * cSB
                                  : (size_t)zb * cSB + (size_t)zh * cSH;

  // XCD-chunked bijective swizzle, then 2-row M-band decode (r10).
  const int nbx = gridDim.x, nby = gridDim.y;
  const int nwg = nbx * nby;
  const int fid = blockIdx.y * nbx + blockIdx.x;
  const int q8 = nwg >> 3, r8 = nwg & 7;
  const int xcd = fid & 7, idx = fid >> 3;
  const int swz = (xcd < r8 ? xcd * (q8 + 1) : r8 * (q8 + 1) + (xcd - r8) * q8) + idx;
  int bx, by;
  if ((nby & 1) == 0) {
    const int W = 2 * nbx;
    const int grp = swz / W, t = swz - grp * W;
    bx = t >> 1; by = grp * 2 + (t & 1);
  } else {
    bx = swz / nby; by = swz - bx * nby;
  }
  const int m0 = by * 256, n0 = bx * 128;

  const int tid = threadIdx.x;
  const int wv = tid >> 6, ln = tid & 63;
  const int wm = wv >> 1, wn = wv & 1;

  // A staging: wave wv covers rows [wv*64, wv*64+64), 4 granules/thread
  const int usA = (ln & 7) ^ (ln >> 3);
  const int rsA = wv * 64 + 2 * (ln >> 3) + (usA >> 2);
  const int ksA = (usA & 3) * 8;
  const __bf16* pA0 = A + (size_t)(m0 + rsA) * ldA + ksA;
  // B staging: all 256 threads cover 128 rows, 2 granules/thread
  const int usB = (tid & 7) ^ ((tid >> 3) & 7);
  const int rsB = 2 * (tid >> 3) + (usB >> 2);
  const int ksB = (usB & 3) * 8;
  const __bf16* pB0 = Bt + (size_t)(n0 + rsB) * ldB + ksB;

  // fragment read offsets (0-conflict scheme, measured r7)
  const int lr = ln & 15;
  const int gfr = ((((ln & 1) << 2) | ((ln >> 4) & 3)) ^ ((ln >> 1) & 7)) << 4;
  const int aR = (wm * 64 + (lr >> 1)) * 128 + gfr;            // + i*1024
  const int bR = 49152 + (wn * 32 + (lr >> 1)) * 128 + gfr;    // + j*1024

  f32x4 acc[8][4] = {};
  const int NT = K >> 5;

#define STG(sl) { \
    char* da = smem + (sl) * 16384 + wv * 4096 + ln * 16; \
    gload_lds16(pA0,            da); \
    gload_lds16(pA0 + 16 * ldA, da + 1024); \
    gload_lds16(pA0 + 32 * ldA, da + 2048); \
    gload_lds16(pA0 + 48 * ldA, da + 3072); \
    char* db = smem + 49152 + (sl) * 8192 + tid * 16; \
    gload_lds16(pB0,            db); \
    gload_lds16(pB0 + 64 * ldB, db + 4096); \
    pA0 += 32; pB0 += 32; }

  // prologue: stage units 0,1 (12 loads); wait unit0 (oldest 6)
  STG(0);
  if (NT > 1) {
    STG(1);
    asm volatile("s_waitcnt vmcnt(6)" ::: "memory");
  } else {
    asm volatile("s_waitcnt vmcnt(0)" ::: "memory");
  }
  __builtin_amdgcn_s_barrier();

  int sc = 0, sn = 1, sf = 2;
  for (int t = 0; t < NT; ++t) {
    if (t + 2 < NT) STG(sf);
    const char* aBase = smem + sc * 16384 + aR;
    const char* bBase = smem + sc * 8192 + bR;   // bR carries the 49152 base
    bf16x8 a[8], b[4];
#pragma unroll
    for (int j = 0; j < 4; j++) b[j] = *(const bf16x8*)(bBase + j * 1024);
#pragma unroll
    for (int i = 0; i < 8; i++) a[i] = *(const bf16x8*)(aBase + i * 1024);
    __builtin_amdgcn_s_setprio(1);
#pragma unroll
    for (int i = 0; i < 8; i++)
#pragma unroll
      for (int j = 0; j < 4; j++)
        acc[i][j] = __builtin_amdgcn_mfma_f32_16x16x32_bf16(a[i], b[j], acc[i][j], 0, 0, 0);
    __builtin_amdgcn_s_setprio(0);
    if (t + 1 < NT) {
      if (t + 2 < NT) { asm volatile("s_waitcnt vmcnt(6)" ::: "memory"); }
      else            { asm volatile("s_waitcnt vmcnt(0)" ::: "memory"); }
      __builtin_amdgcn_sched_barrier(0);
      __builtin_amdgcn_s_barrier();
    }
    const int tmp = sc; sc = sn; sn = sf; sf = tmp;
  }
#undef STG

  // epilogue (C/D mapping: col=lane&15, row=(lane>>4)*4+reg)
  const int rb = m0 + wm * 128 + (ln >> 4) * 4;
  const int cb = n0 + wn * 64 + lr;
#pragma unroll
  for (int i = 0; i < 8; i++)
#pragma unroll
    for (int j = 0; j < 4; j++) {
      const int col = cb + j * 16;
#pragma unroll
      for (int r = 0; r < 4; r++) {
        const int row = rb + i * 16 + r;
        float v = acc[i][j][r];
        const size_t ci = cOff + (size_t)row * ldC + col;
        if (MODE == 0)      ((__bf16*)Cv)[ci] = (__bf16)v;
        else if (MODE == 1) ((float*)Cv)[ci] = v;
        else if (MODE == 2) ((float*)Cv)[ci] = v + bias[col] + res[(size_t)row * ldR + col];
        else if (MODE == 3) { v += bias[col]; ((__bf16*)Cv)[ci] = (__bf16)(v >= 0.f ? v : 0.01f * v); }
        else if (MODE == 4) ((float*)Cv)[ci] = v + bias[col];
        else if (MODE == 5) atomicAdd(&((float*)Cv)[ci], v);
        else if (MODE == 7) ((float*)Cv)[ci] = v;
      }
    }
}

// ---------------- weight transpose + fp32->bf16 ----------------
__global__ void wtrans(const float* __restrict__ W, __bf16* __restrict__ Wt, int K, int N)
{
  const size_t zo = (size_t)blockIdx.z * K * N;
  __shared__ float t[32][33];
  const int n0 = blockIdx.x * 32, k0 = blockIdx.y * 32;
  const int tx = threadIdx.x, ty = threadIdx.y;
#pragma unroll
  for (int r = 0; r < 4; r++)
    t[ty + r * 8][tx] = W[zo + (size_t)(k0 + ty + r * 8) * N + n0 + tx];
  __syncthreads();
#pragma unroll
  for (int r = 0; r < 4; r++)
    Wt[zo + (size_t)(n0 + ty + r * 8) * K + k0 + tx] = (__bf16)t[tx][ty + r * 8];
}

// ---------------- V transpose per (b,h) ----------------
__global__ void vtrans(const __bf16* __restrict__ qkv, __bf16* __restrict__ Vt)
{
  const int z = blockIdx.z, bb = z >> 3, hh = z & 7;
  const __bf16* src = qkv + ((size_t)bb * TT + hh) * (3 * DD) + 2 * DD;
  __bf16* dst = Vt + (size_t)z * DD * 256;
  __shared__ __bf16 t[32][33];
  const int n0 = blockIdx.x * 32, i0 = blockIdx.y * 32;
  const int tx = threadIdx.x, ty = threadIdx.y;
#pragma unroll
  for (int r = 0; r < 4; r++)
    t[ty + r * 8][tx] = src[(size_t)(i0 + ty + r * 8) * (HH * 3 * DD) + n0 + tx];
  __syncthreads();
#pragma unroll
  for (int r = 0; r < 4; r++)
    dst[(size_t)(n0 + ty + r * 8) * 256 + i0 + tx] = t[tx][ty + r * 8];
}

// ---------------- embedding gather ----------------
__global__ void embed_k(const int* __restrict__ x, const float* __restrict__ emb, float* __restrict__ h)
{
  const int row = blockIdx.x;
  const int tok = x[row];
  ((float4*)(h + (size_t)row * DD))[threadIdx.x] = ((const float4*)(emb + (size_t)tok * DD))[threadIdx.x];
}

// ---------------- layernorm row -> bf16 ----------------
__global__ void ln_rows(const float* __restrict__ x, const float* __restrict__ g,
                        const float* __restrict__ b, __bf16* __restrict__ y)
{
  const int row = blockIdx.x, t = threadIdx.x;
  const int wv = t >> 6, ln = t & 63;
  const float4 v = ((const float4*)(x + (size_t)row * DD))[t];
  float s  = v.x + v.y + v.z + v.w;
  float ss = v.x * v.x + v.y * v.y + v.z * v.z + v.w * v.w;
#pragma unroll
  for (int o = 32; o; o >>= 1) { s += __shfl_xor(s, o); ss += __shfl_xor(ss, o); }
  __shared__ float rs_[4], rss_[4];
  if (!ln) { rs_[wv] = s; rss_[wv] = ss; }
  __syncthreads();
  s  = rs_[0] + rs_[1] + rs_[2] + rs_[3];
  ss = rss_[0] + rss_[1] + rss_[2] + rss_[3];
  const float mu  = s * (1.0f / DD);
  const float var = ss * (1.0f / DD) - mu * mu;
  const float r   = rsqrtf(var + 1e-5f);
  const float4 gv = ((const float4*)g)[t];
  const float4 bv = ((const float4*)b)[t];
  bf16x4 o = { (__bf16)((v.x - mu) * r * gv.x + bv.x),
               (__bf16)((v.y - mu) * r * gv.y + bv.y),
               (__bf16)((v.z - mu) * r * gv.z + bv.z),
               (__bf16)((v.w - mu) * r * gv.w + bv.w) };
  ((bf16x4*)(y + (size_t)row * DD))[t] = o;
}

// ---------------- h += sum(partials)+bias2, then layernorm -> bf16 ----------------
__global__ void ln_acc(float* __restrict__ h, const float* __restrict__ P, long pStride,
                       const float* __restrict__ bias2,
                       const float* __restrict__ g, const float* __restrict__ b,
                       __bf16* __restrict__ y)
{
  const int row = blockIdx.x, t = threadIdx.x;
  const int wv = t >> 6, ln = t & 63;
  float4 v = ((const float4*)(h + (size_t)row * DD))[t];
#pragma unroll
  for (int c = 0; c < 4; c++) {
    const float4 p = ((const float4*)(P + (size_t)c * pStride + (size_t)row * DD))[t];
    v.x += p.x; v.y += p.y; v.z += p.z; v.w += p.w;
  }
  const float4 b2 = ((const float4*)bias2)[t];
  v.x += b2.x; v.y += b2.y; v.z += b2.z; v.w += b2.w;
  ((float4*)(h + (size_t)row * DD))[t] = v;
  float s  = v.x + v.y + v.z + v.w;
  float ss = v.x * v.x + v.y * v.y + v.z * v.z + v.w * v.w;
#pragma unroll
  for (int o = 32; o; o >>= 1) { s += __shfl_xor(s, o); ss += __shfl_xor(ss, o); }
  __shared__ float rs_[4], rss_[4];
  if (!ln) { rs_[wv] = s; rss_[wv] = ss; }
  __syncthreads();
  s  = rs_[0] + rs_[1] + rs_[2] + rs_[3];
  ss = rss_[0] + rss_[1] + rss_[2] + rss_[3];
  const float mu  = s * (1.0f / DD);
  const float var = ss * (1.0f / DD) - mu * mu;
  const float r   = rsqrtf(var + 1e-5f);
  const float4 gv = ((const float4*)g)[t];
  const float4 bv = ((const float4*)b)[t];
  bf16x4 o = { (__bf16)((v.x - mu) * r * gv.x + bv.x),
               (__bf16)((v.y - mu) * r * gv.y + bv.y),
               (__bf16)((v.z - mu) * r * gv.z + bv.z),
               (__bf16)((v.w - mu) * r * gv.w + bv.w) };
  ((bf16x4*)(y + (size_t)row * DD))[t] = o;
}

// ---------------- h += sum(partials)+bias2, then fp32->bf16 ----------------
__global__ void f2bf_acc(const float* __restrict__ h, const float* __restrict__ P, long pStride,
                         const float* __restrict__ bias2, __bf16* __restrict__ y)
{
  const int row = blockIdx.x, t = threadIdx.x;
  float4 v = ((const float4*)(h + (size_t)row * DD))[t];
#pragma unroll
  for (int c = 0; c < 4; c++) {
    const float4 p = ((const float4*)(P + (size_t)c * pStride + (size_t)row * DD))[t];
    v.x += p.x; v.y += p.y; v.z += p.z; v.w += p.w;
  }
  const float4 b2 = ((const float4*)bias2)[t];
  bf16x4 o = { (__bf16)(v.x + b2.x), (__bf16)(v.y + b2.y),
               (__bf16)(v.z + b2.z), (__bf16)(v.w + b2.w) };
  ((bf16x4*)(y + (size_t)row * DD))[t] = o;
}

// ---------------- softmax over 256-wide rows -> bf16 ----------------
__global__ void softmax256(const float* __restrict__ S, __bf16* __restrict__ P)
{
  const int row = blockIdx.x, t = threadIdx.x;
  const int wv = t >> 6, ln = t & 63;
  const float v = S[(size_t)row * 256 + t] * SCALE_QK;
  float m = v;
#pragma unroll
  for (int o = 32; o; o >>= 1) m = fmaxf(m, __shfl_xor(m, o));
  __shared__ float red[8];
  if (!ln) red[wv] = m;
  __syncthreads();
  m = fmaxf(fmaxf(red[0], red[1]), fmaxf(red[2], red[3]));
  const float e = __expf(v - m);
  float s = e;
#pragma unroll
  for (int o = 32; o; o >>= 1) s += __shfl_xor(s, o);
  if (!ln) red[4 + wv] = s;
  __syncthreads();
  s = red[4] + red[5] + red[6] + red[7];
  P[(size_t)row * 256 + t] = (__bf16)(e / s);
}

template<int MODE>
static void G(const __bf16* A, long ldA, long aSB, long aSH,
              const __bf16* Bt, long ldB, long bSB, long bSH,
              void* C, long ldC, long cSB, long cSH,
              const float* bias, const float* res, long ldR,
              int M, int N, int K, int Z, hipStream_t s)
{
  hipFuncSetAttribute((const void*)gemm_mt<MODE>,
                      hipFuncAttributeMaxDynamicSharedMemorySize, 73728);
  gemm_mt<MODE><<<dim3(N / 128, M / 256, Z), 256, 73728, s>>>(
      A, ldA, aSB, aSH, Bt, ldB, bSB, bSH, C, ldC, cSB, cSH, bias, res, ldR, K);
}

extern "C" void kernel_launch(void* const* d_in, const int* in_sizes, int n_in,
                              void* d_out, int out_size, void* d_ws, size_t ws_size,
                              hipStream_t stream)
{
  const int*   x       = (const int*)  d_in[0];
  const float* emb     = (const float*)d_in[1];
  const float* ln1_g   = (const float*)d_in[2];
  const float* ln1_b   = (const float*)d_in[3];
  const float* wqkv    = (const float*)d_in[4];
  const float* wout_w  = (const float*)d_in[5];
  const float* wout_b  = (const float*)d_in[6];
  const float* ln2_g   = (const float*)d_in[7];
  const float* ln2_b   = (const float*)d_in[8];
  const float* ff1_w   = (const float*)d_in[9];
  const float* ff1_b   = (const float*)d_in[10];
  const float* ff2_w   = (const float*)d_in[11];
  const float* ff2_b   = (const float*)d_in[12];
  const float* logit_w = (const float*)d_in[13];
  const float* logit_b = (const float*)d_in[14];
  float* out = (float*)d_out;

  const int M = BB * TT;

  char* w = (char*)d_ws;
  size_t off = 0;
  auto take = [&](size_t bytes) { void* p = w + off; off += (bytes + 255) & ~(size_t)255; return p; };
  __bf16* wqkvT = (__bf16*)take((size_t)LL * 3 * DD * DD * 2);
  __bf16* woutT = (__bf16*)take((size_t)LL * DD * DD * 2);
  __bf16* ff1T  = (__bf16*)take((size_t)LL * 4 * DD * DD * 2);
  __bf16* ff2T  = (__bf16*)take((size_t)LL * DD * 4 * DD * 2);
  __bf16* logT  = (__bf16*)take((size_t)VV * DD * 2);
  float*  h     = (float*) take((size_t)M * DD * 4);
  __bf16* ybf   = (__bf16*)take((size_t)M * DD * 2);
  __bf16* qkvbf = (__bf16*)take((size_t)M * 3 * DD * 2);
  float*  Smat  = (float*) take((size_t)BB * HH * 256 * 256 * 4);
  __bf16* Pbf   = (__bf16*)take((size_t)BB * HH * 256 * 256 * 2);
  __bf16* Vt    = (__bf16*)take((size_t)BB * HH * DD * 256 * 2);
  __bf16* Obf   = (__bf16*)take((size_t)M * DD * 2);
  __bf16* midbf = (__bf16*)take((size_t)M * 4 * DD * 2);
  float*  part  = (float*) take((size_t)4 * M * DD * 4);   // ff2 split-K partials
  if (ws_size < off) return;

  const dim3 tb(32, 8);
  wtrans<<<dim3(3 * DD / 32, DD / 32, LL), tb, 0, stream>>>(wqkv,   wqkvT, DD, 3 * DD);
  wtrans<<<dim3(DD / 32,     DD / 32, LL), tb, 0, stream>>>(wout_w, woutT, DD, DD);
  wtrans<<<dim3(4 * DD / 32, DD / 32, LL), tb, 0, stream>>>(ff1_w,  ff1T,  DD, 4 * DD);
  wtrans<<<dim3(DD / 32, 4 * DD / 32, LL), tb, 0, stream>>>(ff2_w,  ff2T,  4 * DD, DD);
  wtrans<<<dim3(VV / 32,     DD / 32, 1),  tb, 0, stream>>>(logit_w, logT, DD, VV);

  embed_k<<<M, 256, 0, stream>>>(x, emb, h);

  for (int l = 0; l < LL; l++) {
    // ln1 (fused with ff2(l-1) partial reduction + residual for l>0)
    if (l == 0)
      ln_rows<<<M, 256, 0, stream>>>(h, ln1_g, ln1_b, ybf);
    else
      ln_acc<<<M, 256, 0, stream>>>(h, part, (long)M * DD, ff2_b + (size_t)(l - 1) * DD,
                                    ln1_g + (size_t)l * DD, ln1_b + (size_t)l * DD, ybf);
    // qkv = y @ wqkv
    G<0>(ybf, DD, 0, 0, wqkvT + (size_t)l * 3 * DD * DD, DD, 0, 0,
         qkvbf, 3 * DD, 0, 0, nullptr, nullptr, 0, M, 3 * DD, DD, 1, stream);
    // S = Q @ K^T  (split-K x4, atomic accumulate into zeroed Smat)
    hipMemsetAsync(Smat, 0, (size_t)BB * HH * 256 * 256 * 4, stream);
    G<5>(qkvbf, HH * 3 * DD, (long)TT * 3 * DD, 3 * DD,
         qkvbf + DD, HH * 3 * DD, (long)TT * 3 * DD, 3 * DD,
         Smat, 256, (long)HH * 256 * 256, 256 * 256,
         nullptr, nullptr, 0, 256, 256, DD / 4, 4 * BB * HH, stream);
    softmax256<<<BB * HH * 256, 256, 0, stream>>>(Smat, Pbf);
    vtrans<<<dim3(DD / 32, 256 / 32, BB * HH), tb, 0, stream>>>(qkvbf, Vt);
    // O = P @ V
    G<0>(Pbf, 256, (long)HH * 256 * 256, 256 * 256,
         Vt, 256, (long)HH * DD * 256, (long)DD * 256,
         Obf, HH * DD, (long)TT * DD, DD,
         nullptr, nullptr, 0, 256, DD, 256, BB * HH, stream);
    // h += O @ wout + b   (MODE 2)
    G<2>(Obf, DD, 0, 0, woutT + (size_t)l * DD * DD, DD, 0, 0,
         h, DD, 0, 0, wout_b + (size_t)l * DD, h, DD, M, DD, DD, 1, stream);
    ln_rows<<<M, 256, 0, stream>>>(h, ln2_g + (size_t)l * DD, ln2_b + (size_t)l * DD, ybf);
    // mid = lrelu(y @ ff1 + b1)
    G<3>(ybf, DD, 0, 0, ff1T + (size_t)l * 4 * DD * DD, DD, 0, 0,
         midbf, 4 * DD, 0, 0, ff1_b + (size_t)l * 4 * DD, nullptr, 0, M, 4 * DD, DD, 1, stream);
    // ff2 partials: part[kc] = mid[:, kc*1024:(kc+1)*1024] @ ff2[kc-chunk]  (512 blocks)
    G<7>(midbf, 4 * DD, 0, 0, ff2T + (size_t)l * DD * 4 * DD, 4 * DD, 0, 0,
         part, DD, (long)M * DD, 0, nullptr, nullptr, 0, M, DD, DD, 4, stream);
  }

  // final: h += sum(partials)+b2(layer3), convert to bf16
  f2bf_acc<<<M, 256, 0, stream>>>(h, part, (long)M * DD, ff2_b + (size_t)3 * DD, ybf);
  // logits = h @ logit_w + logit_b
  G<4>(ybf, DD, 0, 0, logT, DD, 0, 0,
       out, VV, 0, 0, logit_b, nullptr, 0, M, VV, DD, 1, stream);
}

// Round 18
// 1284.942 us; speedup vs baseline: 1.0517x; 1.0143x over previous
//
#include <hip/hip_runtime.h>

#define DD 1024
#define LL 4
#define HH 8
#define BB 2
#define TT 2048
#define VV 32000
#define SCALE_QK 0.08838834764831845f

typedef __bf16 bf16x8 __attribute__((ext_vector_type(8)));
typedef __bf16 bf16x4 __attribute__((ext_vector_type(4)));
typedef float  f32x4  __attribute__((ext_vector_type(4)));

__device__ __forceinline__ void gload_lds16(const void* g, void* l) {
  __builtin_amdgcn_global_load_lds((const __attribute__((address_space(1))) void*)g,
                                   (__attribute__((address_space(3))) void*)l, 16, 0, 0);
}

// =====================================================================
// gemm_mt (r13 config): 256(M)x128(N), BK=32, 16x16x32 MFMA, ring3,
// 2 blocks/CU, counted vmcnt(6), ONE barrier per K-tile, XCD-chunked
// 2-row M-band decode. Used for the fat GEMMs (qkv/ff1/ff2/logits).
// MODE 0: bf16 ; 2: f32 acc+bias+res ; 3: bf16 lrelu(acc+bias) ;
// MODE 4: f32 acc+bias ; 7: split-K partials (plain f32 to Cv+kc*cSB).
// =====================================================================
template<int MODE>
__global__ __launch_bounds__(256, 2)
void gemm_mt(const __bf16* __restrict__ A, long ldA, long aSB, long aSH,
             const __bf16* __restrict__ Bt, long ldB, long bSB, long bSH,
             void* __restrict__ Cv, long ldC, long cSB, long cSH,
             const float* __restrict__ bias,
             const float* __restrict__ res, long ldR,
             int K)
{
  extern __shared__ __attribute__((aligned(16))) char smem[];

  int zbh = blockIdx.z;
  int kc = 0;
  if (MODE == 7) { kc = zbh; zbh = 0; A += (size_t)kc * K; Bt += (size_t)kc * K; }
  const int zb = zbh >> 3, zh = zbh & 7;
  A  += (size_t)zb * aSB + (size_t)zh * aSH;
  Bt += (size_t)zb * bSB + (size_t)zh * bSH;
  const size_t cOff = (MODE == 7) ? (size_t)kc * cSB
                                  : (size_t)zb * cSB + (size_t)zh * cSH;

  // XCD-chunked bijective swizzle, then 2-row M-band decode (r10).
  const int nbx = gridDim.x, nby = gridDim.y;
  const int nwg = nbx * nby;
  const int fid = blockIdx.y * nbx + blockIdx.x;
  const int q8 = nwg >> 3, r8 = nwg & 7;
  const int xcd = fid & 7, idx = fid >> 3;
  const int swz = (xcd < r8 ? xcd * (q8 + 1) : r8 * (q8 + 1) + (xcd - r8) * q8) + idx;
  int bx, by;
  if ((nby & 1) == 0) {
    const int W = 2 * nbx;
    const int grp = swz / W, t = swz - grp * W;
    bx = t >> 1; by = grp * 2 + (t & 1);
  } else {
    bx = swz / nby; by = swz - bx * nby;
  }
  const int m0 = by * 256, n0 = bx * 128;

  const int tid = threadIdx.x;
  const int wv = tid >> 6, ln = tid & 63;
  const int wm = wv >> 1, wn = wv & 1;

  const int usA = (ln & 7) ^ (ln >> 3);
  const int rsA = wv * 64 + 2 * (ln >> 3) + (usA >> 2);
  const int ksA = (usA & 3) * 8;
  const __bf16* pA0 = A + (size_t)(m0 + rsA) * ldA + ksA;
  const int usB = (tid & 7) ^ ((tid >> 3) & 7);
  const int rsB = 2 * (tid >> 3) + (usB >> 2);
  const int ksB = (usB & 3) * 8;
  const __bf16* pB0 = Bt + (size_t)(n0 + rsB) * ldB + ksB;

  const int lr = ln & 15;
  const int gfr = ((((ln & 1) << 2) | ((ln >> 4) & 3)) ^ ((ln >> 1) & 7)) << 4;
  const int aR = (wm * 64 + (lr >> 1)) * 128 + gfr;
  const int bR = 49152 + (wn * 32 + (lr >> 1)) * 128 + gfr;

  f32x4 acc[8][4] = {};
  const int NT = K >> 5;

#define STG(sl) { \
    char* da = smem + (sl) * 16384 + wv * 4096 + ln * 16; \
    gload_lds16(pA0,            da); \
    gload_lds16(pA0 + 16 * ldA, da + 1024); \
    gload_lds16(pA0 + 32 * ldA, da + 2048); \
    gload_lds16(pA0 + 48 * ldA, da + 3072); \
    char* db = smem + 49152 + (sl) * 8192 + tid * 16; \
    gload_lds16(pB0,            db); \
    gload_lds16(pB0 + 64 * ldB, db + 4096); \
    pA0 += 32; pB0 += 32; }

  STG(0);
  if (NT > 1) {
    STG(1);
    asm volatile("s_waitcnt vmcnt(6)" ::: "memory");
  } else {
    asm volatile("s_waitcnt vmcnt(0)" ::: "memory");
  }
  __builtin_amdgcn_s_barrier();

  int sc = 0, sn = 1, sf = 2;
  for (int t = 0; t < NT; ++t) {
    if (t + 2 < NT) STG(sf);
    const char* aBase = smem + sc * 16384 + aR;
    const char* bBase = smem + sc * 8192 + bR;
    bf16x8 a[8], b[4];
#pragma unroll
    for (int j = 0; j < 4; j++) b[j] = *(const bf16x8*)(bBase + j * 1024);
#pragma unroll
    for (int i = 0; i < 8; i++) a[i] = *(const bf16x8*)(aBase + i * 1024);
    __builtin_amdgcn_s_setprio(1);
#pragma unroll
    for (int i = 0; i < 8; i++)
#pragma unroll
      for (int j = 0; j < 4; j++)
        acc[i][j] = __builtin_amdgcn_mfma_f32_16x16x32_bf16(a[i], b[j], acc[i][j], 0, 0, 0);
    __builtin_amdgcn_s_setprio(0);
    if (t + 1 < NT) {
      if (t + 2 < NT) { asm volatile("s_waitcnt vmcnt(6)" ::: "memory"); }
      else            { asm volatile("s_waitcnt vmcnt(0)" ::: "memory"); }
      __builtin_amdgcn_sched_barrier(0);
      __builtin_amdgcn_s_barrier();
    }
    const int tmp = sc; sc = sn; sn = sf; sf = tmp;
  }
#undef STG

  const int rb = m0 + wm * 128 + (ln >> 4) * 4;
  const int cb = n0 + wn * 64 + lr;
#pragma unroll
  for (int i = 0; i < 8; i++)
#pragma unroll
    for (int j = 0; j < 4; j++) {
      const int col = cb + j * 16;
#pragma unroll
      for (int r = 0; r < 4; r++) {
        const int row = rb + i * 16 + r;
        float v = acc[i][j][r];
        const size_t ci = cOff + (size_t)row * ldC + col;
        if (MODE == 0)      ((__bf16*)Cv)[ci] = (__bf16)v;
        else if (MODE == 2) ((float*)Cv)[ci] = v + bias[col] + res[(size_t)row * ldR + col];
        else if (MODE == 3) { v += bias[col]; ((__bf16*)Cv)[ci] = (__bf16)(v >= 0.f ? v : 0.01f * v); }
        else if (MODE == 4) ((float*)Cv)[ci] = v + bias[col];
        else if (MODE == 7) ((float*)Cv)[ci] = v;
      }
    }
}

// =====================================================================
// gemm_rt (verbatim r6, known-correct): 128x128, BK=32, ring3, 3 blocks/CU.
// Used for the small/attention GEMMs (QK, PV, wout) where 256-tile grids
// leave >=50% of CUs idle. MODE 0: bf16 ; 2: f32 acc+bias+res ;
// MODE 5: f32 atomicAdd (split-K, z=(kc<<4)|bh).
// =====================================================================
template<int MODE>
__global__ __launch_bounds__(256, 3)
void gemm_rt(const __bf16* __restrict__ A, long ldA, long aSB, long aSH,
             const __bf16* __restrict__ Bt, long ldB, long bSB, long bSH,
             void* __restrict__ Cv, long ldC, long cSB, long cSH,
             const float* __restrict__ bias,
             const float* __restrict__ res, long ldR,
             int K)
{
  int zbh = blockIdx.z;
  if (MODE == 5) {
    const int kc = zbh >> 4;
    zbh &= 15;
    A  += (size_t)kc * K;
    Bt += (size_t)kc * K;
  }
  const int zb = zbh >> 3, zh = zbh & 7;
  A  += (size_t)zb * aSB + (size_t)zh * aSH;
  Bt += (size_t)zb * bSB + (size_t)zh * bSH;
  const size_t cOff = (size_t)zb * cSB + (size_t)zh * cSH;

  const int nbx = gridDim.x, nby = gridDim.y;
  const int nwg = nbx * nby;
  const int fid = blockIdx.y * nbx + blockIdx.x;
  const int q8 = nwg >> 3, r8 = nwg & 7;
  const int xcd = fid & 7, idx = fid >> 3;
  const int swz = (xcd < r8 ? xcd * (q8 + 1) : r8 * (q8 + 1) + (xcd - r8) * q8) + idx;
  const int bx = swz / nby, by = swz - bx * nby;
  const int m0 = by * 128, n0 = bx * 128;

  __shared__ __attribute__((aligned(16))) char smem[49152];

  const int tid = threadIdx.x;
  const int wv = tid >> 6, ln = tid & 63;
  const int wm = wv >> 1, wn = wv & 1;

  const int ls = tid >> 3;
  const int gs = tid & 7;
  const int us = gs ^ (ls & 7);
  const int rs = 2 * ls + (us >> 2);
  const int ks = (us & 3) * 8;
  const __bf16* pA0 = A  + (size_t)(m0 + rs) * ldA + ks;
  const __bf16* pA1 = A  + (size_t)(m0 + 64 + rs) * ldA + ks;
  const __bf16* pB0 = Bt + (size_t)(n0 + rs) * ldB + ks;
  const __bf16* pB1 = Bt + (size_t)(n0 + 64 + rs) * ldB + ks;

  const int lr = ln & 15;
  const int gfr = ((((ln & 1) << 2) | ((ln >> 4) & 3)) ^ ((ln >> 1) & 7)) << 4;
  const int aR = (wm * 32 + (lr >> 1)) * 128 + gfr;
  const int bR = 24576 + (wn * 32 + (lr >> 1)) * 128 + gfr;

  f32x4 acc[4][4] = {};
  const int NT = K >> 5;

#define STG(sl) { \
    char* da = smem + (sl) * 8192 + tid * 16; \
    gload_lds16(pA0, da); gload_lds16(pA1, da + 4096); \
    char* db = da + 24576; \
    gload_lds16(pB0, db); gload_lds16(pB1, db + 4096); \
    pA0 += 32; pA1 += 32; pB0 += 32; pB1 += 32; }

  STG(0);
  if (NT > 1) {
    STG(1);
    asm volatile("s_waitcnt vmcnt(4)" ::: "memory");
  } else {
    asm volatile("s_waitcnt vmcnt(0)" ::: "memory");
  }
  __builtin_amdgcn_s_barrier();

  int sc = 0, sn = 1, sf = 2;
  for (int t = 0; t < NT; ++t) {
    if (t + 2 < NT) STG(sf);
    const char* ba = smem + sc * 8192;
    bf16x8 a[4], b[4];
#pragma unroll
    for (int i = 0; i < 4; i++) a[i] = *(const bf16x8*)(ba + aR + i * 1024);
#pragma unroll
    for (int j = 0; j < 4; j++) b[j] = *(const bf16x8*)(ba + bR + j * 1024);
    __builtin_amdgcn_s_setprio(1);
#pragma unroll
    for (int i = 0; i < 4; i++)
#pragma unroll
      for (int j = 0; j < 4; j++)
        acc[i][j] = __builtin_amdgcn_mfma_f32_16x16x32_bf16(a[i], b[j], acc[i][j], 0, 0, 0);
    __builtin_amdgcn_s_setprio(0);
    if (t + 1 < NT) {
      if (t + 2 < NT) { asm volatile("s_waitcnt vmcnt(4)" ::: "memory"); }
      else            { asm volatile("s_waitcnt vmcnt(0)" ::: "memory"); }
      __builtin_amdgcn_sched_barrier(0);
      __builtin_amdgcn_s_barrier();
    }
    const int tmp = sc; sc = sn; sn = sf; sf = tmp;
  }
#undef STG

  const int rb = m0 + wm * 64 + (ln >> 4) * 4;
  const int cb = n0 + wn * 64 + (ln & 15);
#pragma unroll
  for (int i = 0; i < 4; i++)
#pragma unroll
    for (int j = 0; j < 4; j++) {
      const int col = cb + j * 16;
#pragma unroll
      for (int r = 0; r < 4; r++) {
        const int row = rb + i * 16 + r;
        float v = acc[i][j][r];
        const size_t ci = cOff + (size_t)row * ldC + col;
        if (MODE == 0)      ((__bf16*)Cv)[ci] = (__bf16)v;
        else if (MODE == 2) ((float*)Cv)[ci] = v + bias[col] + res[(size_t)row * ldR + col];
        else if (MODE == 5) atomicAdd(&((float*)Cv)[ci], v);
      }
    }
}

// ---------------- weight transpose + fp32->bf16 ----------------
__global__ void wtrans(const float* __restrict__ W, __bf16* __restrict__ Wt, int K, int N)
{
  const size_t zo = (size_t)blockIdx.z * K * N;
  __shared__ float t[32][33];
  const int n0 = blockIdx.x * 32, k0 = blockIdx.y * 32;
  const int tx = threadIdx.x, ty = threadIdx.y;
#pragma unroll
  for (int r = 0; r < 4; r++)
    t[ty + r * 8][tx] = W[zo + (size_t)(k0 + ty + r * 8) * N + n0 + tx];
  __syncthreads();
#pragma unroll
  for (int r = 0; r < 4; r++)
    Wt[zo + (size_t)(n0 + ty + r * 8) * K + k0 + tx] = (__bf16)t[tx][ty + r * 8];
}

// ---------------- V transpose per (b,h) ----------------
__global__ void vtrans(const __bf16* __restrict__ qkv, __bf16* __restrict__ Vt)
{
  const int z = blockIdx.z, bb = z >> 3, hh = z & 7;
  const __bf16* src = qkv + ((size_t)bb * TT + hh) * (3 * DD) + 2 * DD;
  __bf16* dst = Vt + (size_t)z * DD * 256;
  __shared__ __bf16 t[32][33];
  const int n0 = blockIdx.x * 32, i0 = blockIdx.y * 32;
  const int tx = threadIdx.x, ty = threadIdx.y;
#pragma unroll
  for (int r = 0; r < 4; r++)
    t[ty + r * 8][tx] = src[(size_t)(i0 + ty + r * 8) * (HH * 3 * DD) + n0 + tx];
  __syncthreads();
#pragma unroll
  for (int r = 0; r < 4; r++)
    dst[(size_t)(n0 + ty + r * 8) * 256 + i0 + tx] = t[tx][ty + r * 8];
}

// ---------------- embedding gather ----------------
__global__ void embed_k(const int* __restrict__ x, const float* __restrict__ emb, float* __restrict__ h)
{
  const int row = blockIdx.x;
  const int tok = x[row];
  ((float4*)(h + (size_t)row * DD))[threadIdx.x] = ((const float4*)(emb + (size_t)tok * DD))[threadIdx.x];
}

// ---------------- layernorm row -> bf16 ----------------
__global__ void ln_rows(const float* __restrict__ x, const float* __restrict__ g,
                        const float* __restrict__ b, __bf16* __restrict__ y)
{
  const int row = blockIdx.x, t = threadIdx.x;
  const int wv = t >> 6, ln = t & 63;
  const float4 v = ((const float4*)(x + (size_t)row * DD))[t];
  float s  = v.x + v.y + v.z + v.w;
  float ss = v.x * v.x + v.y * v.y + v.z * v.z + v.w * v.w;
#pragma unroll
  for (int o = 32; o; o >>= 1) { s += __shfl_xor(s, o); ss += __shfl_xor(ss, o); }
  __shared__ float rs_[4], rss_[4];
  if (!ln) { rs_[wv] = s; rss_[wv] = ss; }
  __syncthreads();
  s  = rs_[0] + rs_[1] + rs_[2] + rs_[3];
  ss = rss_[0] + rss_[1] + rss_[2] + rss_[3];
  const float mu  = s * (1.0f / DD);
  const float var = ss * (1.0f / DD) - mu * mu;
  const float r   = rsqrtf(var + 1e-5f);
  const float4 gv = ((const float4*)g)[t];
  const float4 bv = ((const float4*)b)[t];
  bf16x4 o = { (__bf16)((v.x - mu) * r * gv.x + bv.x),
               (__bf16)((v.y - mu) * r * gv.y + bv.y),
               (__bf16)((v.z - mu) * r * gv.z + bv.z),
               (__bf16)((v.w - mu) * r * gv.w + bv.w) };
  ((bf16x4*)(y + (size_t)row * DD))[t] = o;
}

// ---------------- h += sum(partials)+bias2, then layernorm -> bf16 ----------------
__global__ void ln_acc(float* __restrict__ h, const float* __restrict__ P, long pStride,
                       const float* __restrict__ bias2,
                       const float* __restrict__ g, const float* __restrict__ b,
                       __bf16* __restrict__ y)
{
  const int row = blockIdx.x, t = threadIdx.x;
  const int wv = t >> 6, ln = t & 63;
  float4 v = ((const float4*)(h + (size_t)row * DD))[t];
#pragma unroll
  for (int c = 0; c < 4; c++) {
    const float4 p = ((const float4*)(P + (size_t)c * pStride + (size_t)row * DD))[t];
    v.x += p.x; v.y += p.y; v.z += p.z; v.w += p.w;
  }
  const float4 b2 = ((const float4*)bias2)[t];
  v.x += b2.x; v.y += b2.y; v.z += b2.z; v.w += b2.w;
  ((float4*)(h + (size_t)row * DD))[t] = v;
  float s  = v.x + v.y + v.z + v.w;
  float ss = v.x * v.x + v.y * v.y + v.z * v.z + v.w * v.w;
#pragma unroll
  for (int o = 32; o; o >>= 1) { s += __shfl_xor(s, o); ss += __shfl_xor(ss, o); }
  __shared__ float rs_[4], rss_[4];
  if (!ln) { rs_[wv] = s; rss_[wv] = ss; }
  __syncthreads();
  s  = rs_[0] + rs_[1] + rs_[2] + rs_[3];
  ss = rss_[0] + rss_[1] + rss_[2] + rss_[3];
  const float mu  = s * (1.0f / DD);
  const float var = ss * (1.0f / DD) - mu * mu;
  const float r   = rsqrtf(var + 1e-5f);
  const float4 gv = ((const float4*)g)[t];
  const float4 bv = ((const float4*)b)[t];
  bf16x4 o = { (__bf16)((v.x - mu) * r * gv.x + bv.x),
               (__bf16)((v.y - mu) * r * gv.y + bv.y),
               (__bf16)((v.z - mu) * r * gv.z + bv.z),
               (__bf16)((v.w - mu) * r * gv.w + bv.w) };
  ((bf16x4*)(y + (size_t)row * DD))[t] = o;
}

// ---------------- h += sum(partials)+bias2, then fp32->bf16 ----------------
__global__ void f2bf_acc(const float* __restrict__ h, const float* __restrict__ P, long pStride,
                         const float* __restrict__ bias2, __bf16* __restrict__ y)
{
  const int row = blockIdx.x, t = threadIdx.x;
  float4 v = ((const float4*)(h + (size_t)row * DD))[t];
#pragma unroll
  for (int c = 0; c < 4; c++) {
    const float4 p = ((const float4*)(P + (size_t)c * pStride + (size_t)row * DD))[t];
    v.x += p.x; v.y += p.y; v.z += p.z; v.w += p.w;
  }
  const float4 b2 = ((const float4*)bias2)[t];
  bf16x4 o = { (__bf16)(v.x + b2.x), (__bf16)(v.y + b2.y),
               (__bf16)(v.z + b2.z), (__bf16)(v.w + b2.w) };
  ((bf16x4*)(y + (size_t)row * DD))[t] = o;
}

// ---------------- softmax over 256-wide rows -> bf16 ----------------
__global__ void softmax256(const float* __restrict__ S, __bf16* __restrict__ P)
{
  const int row = blockIdx.x, t = threadIdx.x;
  const int wv = t >> 6, ln = t & 63;
  const float v = S[(size_t)row * 256 + t] * SCALE_QK;
  float m = v;
#pragma unroll
  for (int o = 32; o; o >>= 1) m = fmaxf(m, __shfl_xor(m, o));
  __shared__ float red[8];
  if (!ln) red[wv] = m;
  __syncthreads();
  m = fmaxf(fmaxf(red[0], red[1]), fmaxf(red[2], red[3]));
  const float e = __expf(v - m);
  float s = e;
#pragma unroll
  for (int o = 32; o; o >>= 1) s += __shfl_xor(s, o);
  if (!ln) red[4 + wv] = s;
  __syncthreads();
  s = red[4] + red[5] + red[6] + red[7];
  P[(size_t)row * 256 + t] = (__bf16)(e / s);
}

template<int MODE>
static void G(const __bf16* A, long ldA, long aSB, long aSH,
              const __bf16* Bt, long ldB, long bSB, long bSH,
              void* C, long ldC, long cSB, long cSH,
              const float* bias, const float* res, long ldR,
              int M, int N, int K, int Z, hipStream_t s)
{
  hipFuncSetAttribute((const void*)gemm_mt<MODE>,
                      hipFuncAttributeMaxDynamicSharedMemorySize, 73728);
  gemm_mt<MODE><<<dim3(N / 128, M / 256, Z), 256, 73728, s>>>(
      A, ldA, aSB, aSH, Bt, ldB, bSB, bSH, C, ldC, cSB, cSH, bias, res, ldR, K);
}

template<int MODE>
static void Gr(const __bf16* A, long ldA, long aSB, long aSH,
               const __bf16* Bt, long ldB, long bSB, long bSH,
               void* C, long ldC, long cSB, long cSH,
               const float* bias, const float* res, long ldR,
               int M, int N, int K, int Z, hipStream_t s)
{
  gemm_rt<MODE><<<dim3(N / 128, M / 128, Z), 256, 0, s>>>(
      A, ldA, aSB, aSH, Bt, ldB, bSB, bSH, C, ldC, cSB, cSH, bias, res, ldR, K);
}

extern "C" void kernel_launch(void* const* d_in, const int* in_sizes, int n_in,
                              void* d_out, int out_size, void* d_ws, size_t ws_size,
                              hipStream_t stream)
{
  const int*   x       = (const int*)  d_in[0];
  const float* emb     = (const float*)d_in[1];
  const float* ln1_g   = (const float*)d_in[2];
  const float* ln1_b   = (const float*)d_in[3];
  const float* wqkv    = (const float*)d_in[4];
  const float* wout_w  = (const float*)d_in[5];
  const float* wout_b  = (const float*)d_in[6];
  const float* ln2_g   = (const float*)d_in[7];
  const float* ln2_b   = (const float*)d_in[8];
  const float* ff1_w   = (const float*)d_in[9];
  const float* ff1_b   = (const float*)d_in[10];
  const float* ff2_w   = (const float*)d_in[11];
  const float* ff2_b   = (const float*)d_in[12];
  const float* logit_w = (const float*)d_in[13];
  const float* logit_b = (const float*)d_in[14];
  float* out = (float*)d_out;

  const int M = BB * TT;

  char* w = (char*)d_ws;
  size_t off = 0;
  auto take = [&](size_t bytes) { void* p = w + off; off += (bytes + 255) & ~(size_t)255; return p; };
  __bf16* wqkvT = (__bf16*)take((size_t)LL * 3 * DD * DD * 2);
  __bf16* woutT = (__bf16*)take((size_t)LL * DD * DD * 2);
  __bf16* ff1T  = (__bf16*)take((size_t)LL * 4 * DD * DD * 2);
  __bf16* ff2T  = (__bf16*)take((size_t)LL * DD * 4 * DD * 2);
  __bf16* logT  = (__bf16*)take((size_t)VV * DD * 2);
  float*  h     = (float*) take((size_t)M * DD * 4);
  __bf16* ybf   = (__bf16*)take((size_t)M * DD * 2);
  __bf16* qkvbf = (__bf16*)take((size_t)M * 3 * DD * 2);
  float*  Smat  = (float*) take((size_t)BB * HH * 256 * 256 * 4);
  __bf16* Pbf   = (__bf16*)take((size_t)BB * HH * 256 * 256 * 2);
  __bf16* Vt    = (__bf16*)take((size_t)BB * HH * DD * 256 * 2);
  __bf16* Obf   = (__bf16*)take((size_t)M * DD * 2);
  __bf16* midbf = (__bf16*)take((size_t)M * 4 * DD * 2);
  float*  part  = (float*) take((size_t)4 * M * DD * 4);   // ff2 split-K partials
  if (ws_size < off) return;

  const dim3 tb(32, 8);
  wtrans<<<dim3(3 * DD / 32, DD / 32, LL), tb, 0, stream>>>(wqkv,   wqkvT, DD, 3 * DD);
  wtrans<<<dim3(DD / 32,     DD / 32, LL), tb, 0, stream>>>(wout_w, woutT, DD, DD);
  wtrans<<<dim3(4 * DD / 32, DD / 32, LL), tb, 0, stream>>>(ff1_w,  ff1T,  DD, 4 * DD);
  wtrans<<<dim3(DD / 32, 4 * DD / 32, LL), tb, 0, stream>>>(ff2_w,  ff2T,  4 * DD, DD);
  wtrans<<<dim3(VV / 32,     DD / 32, 1),  tb, 0, stream>>>(logit_w, logT, DD, VV);

  embed_k<<<M, 256, 0, stream>>>(x, emb, h);

  for (int l = 0; l < LL; l++) {
    // ln1 (fused with ff2(l-1) partial reduction + residual for l>0)
    if (l == 0)
      ln_rows<<<M, 256, 0, stream>>>(h, ln1_g, ln1_b, ybf);
    else
      ln_acc<<<M, 256, 0, stream>>>(h, part, (long)M * DD, ff2_b + (size_t)(l - 1) * DD,
                                    ln1_g + (size_t)l * DD, ln1_b + (size_t)l * DD, ybf);
    // qkv = y @ wqkv  (fat: gemm_mt)
    G<0>(ybf, DD, 0, 0, wqkvT + (size_t)l * 3 * DD * DD, DD, 0, 0,
         qkvbf, 3 * DD, 0, 0, nullptr, nullptr, 0, M, 3 * DD, DD, 1, stream);
    // S = Q @ K^T  (small: gemm_rt 128^2, split-K x4 -> 256 blocks)
    hipMemsetAsync(Smat, 0, (size_t)BB * HH * 256 * 256 * 4, stream);
    Gr<5>(qkvbf, HH * 3 * DD, (long)TT * 3 * DD, 3 * DD,
          qkvbf + DD, HH * 3 * DD, (long)TT * 3 * DD, 3 * DD,
          Smat, 256, (long)HH * 256 * 256, 256 * 256,
          nullptr, nullptr, 0, 256, 256, DD / 4, 4 * BB * HH, stream);
    softmax256<<<BB * HH * 256, 256, 0, stream>>>(Smat, Pbf);
    vtrans<<<dim3(DD / 32, 256 / 32, BB * HH), tb, 0, stream>>>(qkvbf, Vt);
    // O = P @ V  (small: gemm_rt -> 256 blocks)
    Gr<0>(Pbf, 256, (long)HH * 256 * 256, 256 * 256,
          Vt, 256, (long)HH * DD * 256, (long)DD * 256,
          Obf, HH * DD, (long)TT * DD, DD,
          nullptr, nullptr, 0, 256, DD, 256, BB * HH, stream);
    // h += O @ wout + b  (small: gemm_rt -> 256 blocks)
    Gr<2>(Obf, DD, 0, 0, woutT + (size_t)l * DD * DD, DD, 0, 0,
          h, DD, 0, 0, wout_b + (size_t)l * DD, h, DD, M, DD, DD, 1, stream);
    ln_rows<<<M, 256, 0, stream>>>(h, ln2_g + (size_t)l * DD, ln2_b + (size_t)l * DD, ybf);
    // mid = lrelu(y @ ff1 + b1)  (fat: gemm_mt)
    G<3>(ybf, DD, 0, 0, ff1T + (size_t)l * 4 * DD * DD, DD, 0, 0,
         midbf, 4 * DD, 0, 0, ff1_b + (size_t)l * 4 * DD, nullptr, 0, M, 4 * DD, DD, 1, stream);
    // ff2 partials (fat: gemm_mt MODE 7, 512 blocks)
    G<7>(midbf, 4 * DD, 0, 0, ff2T + (size_t)l * DD * 4 * DD, 4 * DD, 0, 0,
         part, DD, (long)M * DD, 0, nullptr, nullptr, 0, M, DD, DD, 4, stream);
  }

  // final: h += sum(partials)+b2(layer3), convert to bf16
  f2bf_acc<<<M, 256, 0, stream>>>(h, part, (long)M * DD, ff2_b + (size_t)3 * DD, ybf);
  // logits = h @ logit_w + logit_b  (fat: gemm_mt)
  G<4>(ybf, DD, 0, 0, logT, DD, 0, 0,
       out, VV, 0, 0, logit_b, nullptr, 0, M, VV, DD, 1, stream);
}